// Round 1
// baseline (1805.936 us; speedup 1.0000x reference)
//
#include <hip/hip_runtime.h>
#include <math.h>

#define N_NODES 100000
#define N_EDGES 1600000
#define IN_CH 128
#define HID 64
#define HEADS 2
#define NEG_SLOPE 0.2f

// ---------------- helpers ----------------
__device__ inline void atomicMaxFloat(float* addr, float val) {
    // works for mixed-sign concurrent updates (standard bit-trick)
    if (val >= 0.0f) {
        atomicMax((int*)addr, __float_as_int(val));
    } else {
        atomicMin((unsigned int*)addr, (unsigned int)__float_as_int(val));
    }
}

// ---------------- kernels ----------------

// Zero/seed all workspace accumulators. deg starts at 1.0 (self-loop weight).
__global__ void k_init(float* deg, float* agg1, float* aggGAT,
                       float* amax, float* denom) {
    int idx = blockIdx.x * 256 + threadIdx.x;
    if (idx < N_NODES * 128) aggGAT[idx] = 0.0f;
    if (idx < N_NODES * 64)  agg1[idx]   = 0.0f;
    if (idx < N_NODES)       deg[idx]    = 1.0f;
    if (idx < N_NODES * 2) { amax[idx] = -INFINITY; denom[idx] = 0.0f; }
}

// deg[d] += ew[e]
__global__ void k_deg(const int* __restrict__ dst, const float* __restrict__ ew,
                      float* deg) {
    int e = blockIdx.x * 256 + threadIdx.x;
    if (e < N_EDGES) atomicAdd(&deg[dst[e]], ew[e]);
}

// deg -> deg^{-1/2} in place (deg >= 1 always, so no zero guard needed)
__global__ void k_dinv(float* deg) {
    int n = blockIdx.x * 256 + threadIdx.x;
    if (n < N_NODES) deg[n] = rsqrtf(deg[n]);
}

// h1 = x @ gcn_w   [N,128]@[128,64]
__global__ void k_gemm1(const float* __restrict__ x, const float* __restrict__ w,
                        float* __restrict__ h1) {
    __shared__ float sw[128 * 64];
    __shared__ float sx[4 * 128];
    int t = threadIdx.x;
    for (int i = t; i < 128 * 64; i += 256) sw[i] = w[i];
    int row0 = blockIdx.x * 4;
    for (int i = t; i < 4 * 128; i += 256) {
        int r = row0 + i / 128;
        sx[i] = (r < N_NODES) ? x[r * 128 + (i % 128)] : 0.0f;
    }
    __syncthreads();
    int r = t / 64, c = t % 64;
    int row = row0 + r;
    if (row >= N_NODES) return;
    float acc = 0.0f;
    #pragma unroll 8
    for (int k = 0; k < 128; ++k) acc += sx[r * 128 + k] * sw[k * 64 + c];
    h1[row * 64 + c] = acc;
}

// GCN edge aggregation: agg1[d,c] += dinv[s]*ew*dinv[d] * h1[s,c]
__global__ void k_gcn_agg(const int* __restrict__ src, const int* __restrict__ dst,
                          const float* __restrict__ ew, const float* __restrict__ dinv,
                          const float* __restrict__ h1, float* agg1) {
    long long tid = (long long)blockIdx.x * 256 + threadIdx.x;
    int e = (int)(tid >> 6);
    int c = (int)(tid & 63);
    if (e >= N_EDGES) return;
    int s = src[e], d = dst[e];
    float nrm = dinv[s] * ew[e] * dinv[d];
    atomicAdd(&agg1[d * 64 + c], nrm * h1[s * 64 + c]);
}

// add self-loop term + bias, relu
__global__ void k_gcn_post(const float* __restrict__ dinv, const float* __restrict__ h1,
                           const float* __restrict__ b, float* agg1) {
    int idx = blockIdx.x * 256 + threadIdx.x;
    if (idx >= N_NODES * 64) return;
    int n = idx >> 6, c = idx & 63;
    float di = dinv[n];
    float v = agg1[idx] + di * di * h1[idx] + b[c];
    agg1[idx] = fmaxf(v, 0.0f);
}

// h2 = agg1 @ gat_w   [N,64]@[64,128]
__global__ void k_gemm2(const float* __restrict__ a, const float* __restrict__ w,
                        float* __restrict__ h2) {
    __shared__ float sw[64 * 128];
    __shared__ float sx[2 * 64];
    int t = threadIdx.x;
    for (int i = t; i < 64 * 128; i += 256) sw[i] = w[i];
    int row0 = blockIdx.x * 2;
    for (int i = t; i < 2 * 64; i += 256) {
        int r = row0 + i / 64;
        sx[i] = (r < N_NODES) ? a[r * 64 + (i % 64)] : 0.0f;
    }
    __syncthreads();
    int r = t / 128, c = t % 128;
    int row = row0 + r;
    if (row >= N_NODES) return;
    float acc = 0.0f;
    #pragma unroll 8
    for (int k = 0; k < 64; ++k) acc += sx[r * 64 + k] * sw[k * 128 + c];
    h2[row * 128 + c] = acc;
}

// per-node attention scores: score_s[n,h] = dot(h2[n,h,:], att_src[h,:]); same for dst
__global__ void k_scores(const float* __restrict__ h2, const float* __restrict__ a_src,
                         const float* __restrict__ a_dst,
                         float* score_s, float* score_d) {
    int n = blockIdx.x;
    int t = threadIdx.x;          // 0..127; wave 0 = head 0, wave 1 = head 1
    float hv = h2[n * 128 + t];
    float ps = hv * a_src[t];
    float pd = hv * a_dst[t];
    #pragma unroll
    for (int off = 32; off > 0; off >>= 1) {
        ps += __shfl_down(ps, off, 64);
        pd += __shfl_down(pd, off, 64);
    }
    if ((t & 63) == 0) {
        int h = t >> 6;
        score_s[n * 2 + h] = ps;
        score_d[n * 2 + h] = pd;
    }
}

// alpha = leaky_relu(score_s[s]+score_d[d]); store; segment max over dst.
// index range [0,E) = real edges, [E, E+N) = self loops.
__global__ void k_amax(const int* __restrict__ src, const int* __restrict__ dst,
                       const float* __restrict__ score_s, const float* __restrict__ score_d,
                       float* alpha, float* amax) {
    int e = blockIdx.x * 256 + threadIdx.x;
    if (e >= N_EDGES + N_NODES) return;
    int s, d;
    if (e < N_EDGES) { s = src[e]; d = dst[e]; } else { s = d = e - N_EDGES; }
    #pragma unroll
    for (int h = 0; h < 2; ++h) {
        float a = score_s[s * 2 + h] + score_d[d * 2 + h];
        a = (a >= 0.0f) ? a : NEG_SLOPE * a;
        alpha[e * 2 + h] = a;
        atomicMaxFloat(&amax[d * 2 + h], a);
    }
}

// ex = exp(alpha - amax[d]); overwrite alpha with ex; denom[d] += ex
__global__ void k_expsum(const int* __restrict__ dst, const float* __restrict__ amax,
                         float* alpha, float* denom) {
    int e = blockIdx.x * 256 + threadIdx.x;
    if (e >= N_EDGES + N_NODES) return;
    int d = (e < N_EDGES) ? dst[e] : e - N_EDGES;
    #pragma unroll
    for (int h = 0; h < 2; ++h) {
        float ex = expf(alpha[e * 2 + h] - amax[d * 2 + h]);
        alpha[e * 2 + h] = ex;
        atomicAdd(&denom[d * 2 + h], ex);
    }
}

// aggGAT[d, h*64+c] += (ex/denom[d,h]) * h2[s, h*64+c]
__global__ void k_gat_agg(const int* __restrict__ src, const int* __restrict__ dst,
                          const float* __restrict__ alpha, const float* __restrict__ denom,
                          const float* __restrict__ h2, float* aggGAT) {
    int e = blockIdx.x;
    int t = threadIdx.x;          // 0..127
    int h = t >> 6;
    int s, d;
    if (e < N_EDGES) { s = src[e]; d = dst[e]; } else { s = d = e - N_EDGES; }
    float coef = alpha[e * 2 + h] / fmaxf(denom[d * 2 + h], 1e-16f);
    atomicAdd(&aggGAT[d * 128 + t], coef * h2[s * 128 + t]);
}

// out = relu(mean over heads + bias)
__global__ void k_final(const float* __restrict__ aggGAT, const float* __restrict__ b,
                        float* __restrict__ out) {
    int idx = blockIdx.x * 256 + threadIdx.x;
    if (idx >= N_NODES * 64) return;
    int n = idx >> 6, c = idx & 63;
    float v = 0.5f * (aggGAT[n * 128 + c] + aggGAT[n * 128 + 64 + c]) + b[c];
    out[idx] = fmaxf(v, 0.0f);
}

// ---------------- launch ----------------
extern "C" void kernel_launch(void* const* d_in, const int* in_sizes, int n_in,
                              void* d_out, int out_size, void* d_ws, size_t ws_size,
                              hipStream_t stream) {
    const float* x       = (const float*)d_in[0];
    const int*   eidx    = (const int*)d_in[1];
    const float* ew      = (const float*)d_in[2];
    const float* gcn_w   = (const float*)d_in[3];
    const float* gcn_b   = (const float*)d_in[4];
    const float* gat_w   = (const float*)d_in[5];
    const float* att_src = (const float*)d_in[6];
    const float* att_dst = (const float*)d_in[7];
    const float* gat_b   = (const float*)d_in[8];
    float* out = (float*)d_out;

    const int* src = eidx;            // edge_index[0]
    const int* dst = eidx + N_EDGES;  // edge_index[1]

    // workspace layout (floats)
    float* ws      = (float*)d_ws;
    float* dinv    = ws;                                   // N
    float* h1      = dinv + N_NODES;                       // N*64
    float* agg1    = h1 + (size_t)N_NODES * 64;            // N*64
    float* h2      = agg1 + (size_t)N_NODES * 64;          // N*128
    float* score_s = h2 + (size_t)N_NODES * 128;           // N*2
    float* score_d = score_s + (size_t)N_NODES * 2;        // N*2
    float* amax    = score_d + (size_t)N_NODES * 2;        // N*2
    float* denom   = amax + (size_t)N_NODES * 2;           // N*2
    float* alpha   = denom + (size_t)N_NODES * 2;          // (E+N)*2
    float* aggGAT  = alpha + (size_t)(N_EDGES + N_NODES) * 2; // N*128

    const int T = 256;

    k_init<<<(N_NODES * 128 + T - 1) / T, T, 0, stream>>>(dinv, agg1, aggGAT, amax, denom);
    k_gemm1<<<(N_NODES + 3) / 4, T, 0, stream>>>(x, gcn_w, h1);
    k_deg<<<(N_EDGES + T - 1) / T, T, 0, stream>>>(dst, ew, dinv);
    k_dinv<<<(N_NODES + T - 1) / T, T, 0, stream>>>(dinv);
    k_gcn_agg<<<(int)(((long long)N_EDGES * 64 + T - 1) / T), T, 0, stream>>>(src, dst, ew, dinv, h1, agg1);
    k_gcn_post<<<(N_NODES * 64 + T - 1) / T, T, 0, stream>>>(dinv, h1, gcn_b, agg1);
    k_gemm2<<<(N_NODES + 1) / 2, T, 0, stream>>>(agg1, gat_w, h2);
    k_scores<<<N_NODES, 128, 0, stream>>>(h2, att_src, att_dst, score_s, score_d);
    k_amax<<<(N_EDGES + N_NODES + T - 1) / T, T, 0, stream>>>(src, dst, score_s, score_d, alpha, amax);
    k_expsum<<<(N_EDGES + N_NODES + T - 1) / T, T, 0, stream>>>(dst, amax, alpha, denom);
    k_gat_agg<<<N_EDGES + N_NODES, 128, 0, stream>>>(src, dst, alpha, denom, h2, aggGAT);
    k_final<<<(N_NODES * 64 + T - 1) / T, T, 0, stream>>>(aggGAT, gat_b, out);
}

// Round 2
// 1034.017 us; speedup vs baseline: 1.7465x; 1.7465x over previous
//
#include <hip/hip_runtime.h>
#include <math.h>

#define N_NODES 100000
#define N_EDGES 1600000
#define IN_CH 128
#define HID 64
#define HEADS 2
#define NEG_SLOPE 0.2f

#define NB_SCAN ((N_NODES + 255) / 256)   // 391 scan blocks

// ---------------- CSR build ----------------

// count=0, deg=1.0 (self-loop weight)
__global__ void k_init(int* count, float* deg) {
    int n = blockIdx.x * 256 + threadIdx.x;
    if (n < N_NODES) { count[n] = 0; deg[n] = 1.0f; }
}

// histogram by dst + weighted in-degree
__global__ void k_count_deg(const int* __restrict__ dst, const float* __restrict__ ew,
                            int* count, float* deg) {
    int e = blockIdx.x * 256 + threadIdx.x;
    if (e >= N_EDGES) return;
    int d = dst[e];
    atomicAdd(&count[d], 1);
    atomicAdd(&deg[d], ew[e]);
}

__global__ void k_dinv(float* deg) {
    int n = blockIdx.x * 256 + threadIdx.x;
    if (n < N_NODES) deg[n] = rsqrtf(deg[n]);
}

// per-block inclusive scan of count -> incl, block totals -> bsum
__global__ void k_scan_a(const int* __restrict__ count, int* __restrict__ incl,
                         int* __restrict__ bsum) {
    __shared__ int sh[256];
    int tid = threadIdx.x;
    int g = blockIdx.x * 256 + tid;
    int v = (g < N_NODES) ? count[g] : 0;
    sh[tid] = v;
    __syncthreads();
    for (int off = 1; off < 256; off <<= 1) {
        int t = (tid >= off) ? sh[tid - off] : 0;
        __syncthreads();
        sh[tid] += t;
        __syncthreads();
    }
    if (g < N_NODES) incl[g] = sh[tid];
    if (tid == 255) bsum[blockIdx.x] = sh[255];
}

// exclusive scan of the 391 block sums (single block, 512 threads)
__global__ void k_scan_b(const int* __restrict__ bsum, int* __restrict__ boff) {
    __shared__ int sh[512];
    int tid = threadIdx.x;
    int v = (tid < NB_SCAN) ? bsum[tid] : 0;
    sh[tid] = v;
    __syncthreads();
    for (int off = 1; off < 512; off <<= 1) {
        int t = (tid >= off) ? sh[tid - off] : 0;
        __syncthreads();
        sh[tid] += t;
        __syncthreads();
    }
    if (tid < NB_SCAN) boff[tid] = sh[tid] - v;   // exclusive
}

// rowptr / cursor from incl + boff
__global__ void k_scan_c(const int* __restrict__ count, const int* __restrict__ incl,
                         const int* __restrict__ boff, int* rowptr, int* cursor) {
    int g = blockIdx.x * 256 + threadIdx.x;
    if (g >= N_NODES) return;
    int excl = incl[g] - count[g] + boff[blockIdx.x];
    rowptr[g] = excl;
    cursor[g] = excl;
    if (g == N_NODES - 1) rowptr[N_NODES] = incl[g] + boff[blockIdx.x];
}

// scatter edges into CSR order; precompute GCN edge norm
__global__ void k_scatter(const int* __restrict__ src, const int* __restrict__ dst,
                          const float* __restrict__ ew, const float* __restrict__ dinv,
                          int* cursor, int* __restrict__ es, float* __restrict__ enrm) {
    int e = blockIdx.x * 256 + threadIdx.x;
    if (e >= N_EDGES) return;
    int s = src[e], d = dst[e];
    int pos = atomicAdd(&cursor[d], 1);
    es[pos] = s;
    enrm[pos] = dinv[s] * ew[e] * dinv[d];
}

// ---------------- dense ----------------

// h1 = x @ gcn_w   [N,128]@[128,64]
__global__ void k_gemm1(const float* __restrict__ x, const float* __restrict__ w,
                        float* __restrict__ h1) {
    __shared__ float sw[128 * 64];
    __shared__ float sx[4 * 128];
    int t = threadIdx.x;
    for (int i = t; i < 128 * 64; i += 256) sw[i] = w[i];
    int row0 = blockIdx.x * 4;
    for (int i = t; i < 4 * 128; i += 256) {
        int r = row0 + i / 128;
        sx[i] = (r < N_NODES) ? x[r * 128 + (i % 128)] : 0.0f;
    }
    __syncthreads();
    int r = t / 64, c = t % 64;
    int row = row0 + r;
    if (row >= N_NODES) return;
    float acc = 0.0f;
    #pragma unroll 8
    for (int k = 0; k < 128; ++k) acc += sx[r * 128 + k] * sw[k * 64 + c];
    h1[row * 64 + c] = acc;
}

// h2 = agg1 @ gat_w   [N,64]@[64,128]
__global__ void k_gemm2(const float* __restrict__ a, const float* __restrict__ w,
                        float* __restrict__ h2) {
    __shared__ float sw[64 * 128];
    __shared__ float sx[2 * 64];
    int t = threadIdx.x;
    for (int i = t; i < 64 * 128; i += 256) sw[i] = w[i];
    int row0 = blockIdx.x * 2;
    for (int i = t; i < 2 * 64; i += 256) {
        int r = row0 + i / 64;
        sx[i] = (r < N_NODES) ? a[r * 64 + (i % 64)] : 0.0f;
    }
    __syncthreads();
    int r = t / 128, c = t % 128;
    int row = row0 + r;
    if (row >= N_NODES) return;
    float acc = 0.0f;
    #pragma unroll 8
    for (int k = 0; k < 64; ++k) acc += sx[r * 64 + k] * sw[k * 128 + c];
    h2[row * 128 + c] = acc;
}

// ---------------- segment gather kernels (no atomics) ----------------

// GCN: per node, lane=channel; agg1[n,c] = relu(dinv[n]^2*h1[n,c] + sum_e nrm*h1[s,c] + b[c])
__global__ void k_gcn_agg_csr(const int* __restrict__ rowptr, const int* __restrict__ es,
                              const float* __restrict__ enrm, const float* __restrict__ dinv,
                              const float* __restrict__ h1, const float* __restrict__ b,
                              float* __restrict__ agg1) {
    int t = threadIdx.x;
    int n = blockIdx.x * 4 + (t >> 6);
    int lane = t & 63;
    if (n >= N_NODES) return;
    int r0 = rowptr[n], r1 = rowptr[n + 1];
    float di = dinv[n];
    float acc = di * di * h1[n * 64 + lane];
    for (int i = r0; i < r1; ++i) {
        int s = es[i];
        float w = enrm[i];
        acc += w * h1[s * 64 + lane];
    }
    agg1[n * 64 + lane] = fmaxf(acc + b[lane], 0.0f);
}

// attention scores per node
__global__ void k_scores(const float* __restrict__ h2, const float* __restrict__ a_src,
                         const float* __restrict__ a_dst,
                         float* score_s, float* score_d) {
    int n = blockIdx.x;
    int t = threadIdx.x;          // 0..127; wave 0 = head 0, wave 1 = head 1
    float hv = h2[n * 128 + t];
    float ps = hv * a_src[t];
    float pd = hv * a_dst[t];
    #pragma unroll
    for (int off = 32; off > 0; off >>= 1) {
        ps += __shfl_down(ps, off, 64);
        pd += __shfl_down(pd, off, 64);
    }
    if ((t & 63) == 0) {
        int h = t >> 6;
        score_s[n * 2 + h] = ps;
        score_d[n * 2 + h] = pd;
    }
}

__device__ inline float leaky(float a) { return (a >= 0.0f) ? a : NEG_SLOPE * a; }

// GAT: block=128 -> 1 node, wave h = head h, lane = channel.
// pass1: segment max (incl self-loop); pass2: unnormalized expsum + aggregate; scale; mean-heads.
__global__ void k_gat_csr(const int* __restrict__ rowptr, const int* __restrict__ es,
                          const float* __restrict__ score_s, const float* __restrict__ score_d,
                          const float* __restrict__ h2, const float* __restrict__ b,
                          float* __restrict__ out) {
    __shared__ float lds[128];
    int n = blockIdx.x;
    int t = threadIdx.x;
    int head = t >> 6, lane = t & 63;
    int r0 = rowptr[n], r1 = rowptr[n + 1];
    float sdn = score_d[n * 2 + head];
    float a_self = leaky(score_s[n * 2 + head] + sdn);
    // pass 1: max
    float m = a_self;
    for (int i = r0; i < r1; ++i) {
        float a = leaky(score_s[es[i] * 2 + head] + sdn);
        m = fmaxf(m, a);
    }
    // pass 2: expsum + aggregate (unnormalized)
    float ex_self = __expf(a_self - m);
    float den = ex_self;
    float acc = ex_self * h2[n * 128 + head * 64 + lane];
    for (int i = r0; i < r1; ++i) {
        int s = es[i];
        float ex = __expf(leaky(score_s[s * 2 + head] + sdn) - m);
        den += ex;
        acc += ex * h2[s * 128 + head * 64 + lane];
    }
    acc /= fmaxf(den, 1e-16f);
    lds[t] = acc;
    __syncthreads();
    if (t < 64) {
        float v = 0.5f * (lds[t] + lds[64 + t]) + b[t];
        out[n * 64 + t] = fmaxf(v, 0.0f);
    }
}

// ---------------- launch ----------------
extern "C" void kernel_launch(void* const* d_in, const int* in_sizes, int n_in,
                              void* d_out, int out_size, void* d_ws, size_t ws_size,
                              hipStream_t stream) {
    const float* x       = (const float*)d_in[0];
    const int*   eidx    = (const int*)d_in[1];
    const float* ew      = (const float*)d_in[2];
    const float* gcn_w   = (const float*)d_in[3];
    const float* gcn_b   = (const float*)d_in[4];
    const float* gat_w   = (const float*)d_in[5];
    const float* att_src = (const float*)d_in[6];
    const float* att_dst = (const float*)d_in[7];
    const float* gat_b   = (const float*)d_in[8];
    float* out = (float*)d_out;

    const int* src = eidx;            // edge_index[0]
    const int* dst = eidx + N_EDGES;  // edge_index[1]

    // workspace layout
    char* p = (char*)d_ws;
    float* deg     = (float*)p; p += sizeof(float) * N_NODES;        // deg -> dinv in place
    int*   count   = (int*)p;   p += sizeof(int) * N_NODES;
    int*   incl    = (int*)p;   p += sizeof(int) * N_NODES;
    int*   bsum    = (int*)p;   p += sizeof(int) * NB_SCAN;
    int*   boff    = (int*)p;   p += sizeof(int) * NB_SCAN;
    int*   rowptr  = (int*)p;   p += sizeof(int) * (N_NODES + 1);
    int*   cursor  = (int*)p;   p += sizeof(int) * N_NODES;
    int*   es      = (int*)p;   p += sizeof(int) * N_EDGES;
    float* enrm    = (float*)p; p += sizeof(float) * N_EDGES;
    float* h1      = (float*)p; p += sizeof(float) * (size_t)N_NODES * 64;
    float* agg1    = (float*)p; p += sizeof(float) * (size_t)N_NODES * 64;
    float* h2      = (float*)p; p += sizeof(float) * (size_t)N_NODES * 128;
    float* score_s = (float*)p; p += sizeof(float) * N_NODES * 2;
    float* score_d = (float*)p; p += sizeof(float) * N_NODES * 2;

    const int T = 256;
    const int NBn = (N_NODES + T - 1) / T;
    const int NBe = (N_EDGES + T - 1) / T;

    // CSR build
    k_init<<<NBn, T, 0, stream>>>(count, deg);
    k_count_deg<<<NBe, T, 0, stream>>>(dst, ew, count, deg);
    k_dinv<<<NBn, T, 0, stream>>>(deg);
    k_scan_a<<<NB_SCAN, T, 0, stream>>>(count, incl, bsum);
    k_scan_b<<<1, 512, 0, stream>>>(bsum, boff);
    k_scan_c<<<NB_SCAN, T, 0, stream>>>(count, incl, boff, rowptr, cursor);
    k_scatter<<<NBe, T, 0, stream>>>(src, dst, ew, deg, cursor, es, enrm);

    // layer 1: GCN
    k_gemm1<<<(N_NODES + 3) / 4, T, 0, stream>>>(x, gcn_w, h1);
    k_gcn_agg_csr<<<(N_NODES + 3) / 4, T, 0, stream>>>(rowptr, es, enrm, deg, h1, gcn_b, agg1);

    // layer 2: GAT
    k_gemm2<<<(N_NODES + 1) / 2, T, 0, stream>>>(agg1, gat_w, h2);
    k_scores<<<N_NODES, 128, 0, stream>>>(h2, att_src, att_dst, score_s, score_d);
    k_gat_csr<<<N_NODES, 128, 0, stream>>>(rowptr, es, score_s, score_d, h2, gat_b, out);
}

// Round 3
// 663.577 us; speedup vs baseline: 2.7215x; 1.5582x over previous
//
#include <hip/hip_runtime.h>
#include <math.h>

#define N_NODES 100000
#define N_EDGES 1600000
#define IN_CH 128
#define HID 64
#define HEADS 2
#define NEG_SLOPE 0.2f

#define NB_SCAN ((N_NODES + 255) / 256)   // 391 scan blocks

// ---------------- CSR build ----------------

__global__ void k_init(int* count, float* deg) {
    int n = blockIdx.x * 256 + threadIdx.x;
    if (n < N_NODES) { count[n] = 0; deg[n] = 1.0f; }
}

__global__ void k_count_deg(const int* __restrict__ dst, const float* __restrict__ ew,
                            int* count, float* deg) {
    int e = blockIdx.x * 256 + threadIdx.x;
    if (e >= N_EDGES) return;
    int d = dst[e];
    atomicAdd(&count[d], 1);
    atomicAdd(&deg[d], ew[e]);
}

__global__ void k_dinv(float* deg) {
    int n = blockIdx.x * 256 + threadIdx.x;
    if (n < N_NODES) deg[n] = rsqrtf(deg[n]);
}

__global__ void k_scan_a(const int* __restrict__ count, int* __restrict__ incl,
                         int* __restrict__ bsum) {
    __shared__ int sh[256];
    int tid = threadIdx.x;
    int g = blockIdx.x * 256 + tid;
    int v = (g < N_NODES) ? count[g] : 0;
    sh[tid] = v;
    __syncthreads();
    for (int off = 1; off < 256; off <<= 1) {
        int t = (tid >= off) ? sh[tid - off] : 0;
        __syncthreads();
        sh[tid] += t;
        __syncthreads();
    }
    if (g < N_NODES) incl[g] = sh[tid];
    if (tid == 255) bsum[blockIdx.x] = sh[255];
}

__global__ void k_scan_b(const int* __restrict__ bsum, int* __restrict__ boff) {
    __shared__ int sh[512];
    int tid = threadIdx.x;
    int v = (tid < NB_SCAN) ? bsum[tid] : 0;
    sh[tid] = v;
    __syncthreads();
    for (int off = 1; off < 512; off <<= 1) {
        int t = (tid >= off) ? sh[tid - off] : 0;
        __syncthreads();
        sh[tid] += t;
        __syncthreads();
    }
    if (tid < NB_SCAN) boff[tid] = sh[tid] - v;   // exclusive
}

__global__ void k_scan_c(const int* __restrict__ count, const int* __restrict__ incl,
                         const int* __restrict__ boff, int* rowptr, int* cursor) {
    int g = blockIdx.x * 256 + threadIdx.x;
    if (g >= N_NODES) return;
    int excl = incl[g] - count[g] + boff[blockIdx.x];
    rowptr[g] = excl;
    cursor[g] = excl;
    if (g == N_NODES - 1) rowptr[N_NODES] = incl[g] + boff[blockIdx.x];
}

// scatter edges into CSR order; pack {src, gcn_norm} into int2 (one 8B store)
__global__ void k_scatter(const int* __restrict__ src, const int* __restrict__ dst,
                          const float* __restrict__ ew, const float* __restrict__ dinv,
                          int* cursor, int2* __restrict__ ep) {
    int e = blockIdx.x * 256 + threadIdx.x;
    if (e >= N_EDGES) return;
    int s = src[e], d = dst[e];
    int pos = atomicAdd(&cursor[d], 1);
    float nrm = dinv[s] * ew[e] * dinv[d];
    ep[pos] = make_int2(s, __float_as_int(nrm));
}

// ---------------- dense: register-tiled GEMMs ----------------

// h1 = x @ gcn_w   [N,128]@[128,64], 64-row tiles, 4x4 micro-tile
__global__ __launch_bounds__(256) void k_gemm1(const float* __restrict__ x,
                                               const float* __restrict__ w,
                                               float* __restrict__ h1) {
    __shared__ float sxT[128][64];   // [k][r]
    __shared__ float sw[128][64];    // [k][c]
    int t = threadIdx.x;
    int tx = t & 15, ty = t >> 4;
    int row0 = blockIdx.x * 64;
    for (int i = t; i < 128 * 16; i += 256)          // w: 8192 floats = 2048 float4
        ((float4*)sw)[i] = ((const float4*)w)[i];
    for (int i = t; i < 64 * 32; i += 256) {          // x tile: 64 rows x 32 float4
        int r = i >> 5, kq = i & 31;
        int row = row0 + r;
        float4 v = make_float4(0.f, 0.f, 0.f, 0.f);
        if (row < N_NODES) v = ((const float4*)x)[row * 32 + kq];
        int k = kq * 4;
        sxT[k][r] = v.x; sxT[k + 1][r] = v.y; sxT[k + 2][r] = v.z; sxT[k + 3][r] = v.w;
    }
    __syncthreads();
    float acc[4][4] = {};
    for (int k = 0; k < 128; ++k) {
        float4 a = *(const float4*)&sxT[k][ty * 4];
        float4 bb = *(const float4*)&sw[k][tx * 4];
        acc[0][0] += a.x * bb.x; acc[0][1] += a.x * bb.y; acc[0][2] += a.x * bb.z; acc[0][3] += a.x * bb.w;
        acc[1][0] += a.y * bb.x; acc[1][1] += a.y * bb.y; acc[1][2] += a.y * bb.z; acc[1][3] += a.y * bb.w;
        acc[2][0] += a.z * bb.x; acc[2][1] += a.z * bb.y; acc[2][2] += a.z * bb.z; acc[2][3] += a.z * bb.w;
        acc[3][0] += a.w * bb.x; acc[3][1] += a.w * bb.y; acc[3][2] += a.w * bb.z; acc[3][3] += a.w * bb.w;
    }
    #pragma unroll
    for (int i = 0; i < 4; ++i) {
        int row = row0 + ty * 4 + i;
        if (row < N_NODES)
            ((float4*)h1)[row * 16 + tx] = make_float4(acc[i][0], acc[i][1], acc[i][2], acc[i][3]);
    }
}

// h2 = agg1 @ gat_w   [N,64]@[64,128]; grid = tiles x 2 column halves
__global__ __launch_bounds__(256) void k_gemm2(const float* __restrict__ a,
                                               const float* __restrict__ w,
                                               float* __restrict__ h2) {
    __shared__ float sxT[64][64];    // [k][r]
    __shared__ float swh[64][64];    // [k][c] (column half)
    int t = threadIdx.x;
    int tx = t & 15, ty = t >> 4;
    int tile = blockIdx.x >> 1, half = blockIdx.x & 1;
    int row0 = tile * 64;
    for (int i = t; i < 64 * 16; i += 256) {          // w half: rows 64, cols 64
        int k = i >> 4, cq = i & 15;
        float4 v = ((const float4*)(w + k * 128 + half * 64))[cq];
        ((float4*)&swh[k][cq * 4])[0] = v;
    }
    for (int i = t; i < 64 * 16; i += 256) {          // a tile: 64 rows x 16 float4
        int r = i >> 4, kq = i & 15;
        int row = row0 + r;
        float4 v = make_float4(0.f, 0.f, 0.f, 0.f);
        if (row < N_NODES) v = ((const float4*)a)[row * 16 + kq];
        int k = kq * 4;
        sxT[k][r] = v.x; sxT[k + 1][r] = v.y; sxT[k + 2][r] = v.z; sxT[k + 3][r] = v.w;
    }
    __syncthreads();
    float acc[4][4] = {};
    for (int k = 0; k < 64; ++k) {
        float4 av = *(const float4*)&sxT[k][ty * 4];
        float4 bb = *(const float4*)&swh[k][tx * 4];
        acc[0][0] += av.x * bb.x; acc[0][1] += av.x * bb.y; acc[0][2] += av.x * bb.z; acc[0][3] += av.x * bb.w;
        acc[1][0] += av.y * bb.x; acc[1][1] += av.y * bb.y; acc[1][2] += av.y * bb.z; acc[1][3] += av.y * bb.w;
        acc[2][0] += av.z * bb.x; acc[2][1] += av.z * bb.y; acc[2][2] += av.z * bb.z; acc[2][3] += av.z * bb.w;
        acc[3][0] += av.w * bb.x; acc[3][1] += av.w * bb.y; acc[3][2] += av.w * bb.z; acc[3][3] += av.w * bb.w;
    }
    #pragma unroll
    for (int i = 0; i < 4; ++i) {
        int row = row0 + ty * 4 + i;
        if (row < N_NODES)
            ((float4*)h2)[row * 32 + half * 16 + tx] = make_float4(acc[i][0], acc[i][1], acc[i][2], acc[i][3]);
    }
}

// ---------------- segment gather kernels ----------------

// GCN: wave = node; lanes = 4 edge-groups x 16 (float4 channels).
__global__ void k_gcn_csr(const int* __restrict__ rowptr, const int2* __restrict__ ep,
                          const float* __restrict__ dinv, const float4* __restrict__ h1v,
                          const float* __restrict__ b, float4* __restrict__ agg1v) {
    int t = threadIdx.x;
    int n = blockIdx.x * 4 + (t >> 6);
    if (n >= N_NODES) return;
    int lane = t & 63, q = lane >> 4, r = lane & 15;
    int r0 = rowptr[n], r1 = rowptr[n + 1];
    float4 acc = make_float4(0.f, 0.f, 0.f, 0.f);
    if (q == 0) {
        float di = dinv[n];
        float wl = di * di;
        float4 v = h1v[n * 16 + r];
        acc.x = wl * v.x; acc.y = wl * v.y; acc.z = wl * v.z; acc.w = wl * v.w;
    }
    for (int i = r0 + q; i < r1; i += 4) {
        int2 e = ep[i];
        float wl = __int_as_float(e.y);
        float4 v = h1v[e.x * 16 + r];
        acc.x += wl * v.x; acc.y += wl * v.y; acc.z += wl * v.z; acc.w += wl * v.w;
    }
    #pragma unroll
    for (int off = 16; off < 64; off <<= 1) {
        acc.x += __shfl_xor(acc.x, off, 64);
        acc.y += __shfl_xor(acc.y, off, 64);
        acc.z += __shfl_xor(acc.z, off, 64);
        acc.w += __shfl_xor(acc.w, off, 64);
    }
    if (q == 0) {
        float4 bb = ((const float4*)b)[r];
        agg1v[n * 16 + r] = make_float4(fmaxf(acc.x + bb.x, 0.f), fmaxf(acc.y + bb.y, 0.f),
                                        fmaxf(acc.z + bb.z, 0.f), fmaxf(acc.w + bb.w, 0.f));
    }
}

// attention scores per node
__global__ void k_scores(const float* __restrict__ h2, const float* __restrict__ a_src,
                         const float* __restrict__ a_dst,
                         float* score_s, float* score_d) {
    int n = blockIdx.x;
    int t = threadIdx.x;          // 0..127; wave 0 = head 0, wave 1 = head 1
    float hv = h2[n * 128 + t];
    float ps = hv * a_src[t];
    float pd = hv * a_dst[t];
    #pragma unroll
    for (int off = 32; off > 0; off >>= 1) {
        ps += __shfl_down(ps, off, 64);
        pd += __shfl_down(pd, off, 64);
    }
    if ((t & 63) == 0) {
        int h = t >> 6;
        score_s[n * 2 + h] = ps;
        score_d[n * 2 + h] = pd;
    }
}

__device__ inline float leaky(float a) { return (a >= 0.0f) ? a : NEG_SLOPE * a; }

// GAT: block=128 -> 1 node; wave = head; lanes = 4 edge-groups x 16 (float4 channels).
__global__ void k_gat_csr(const int* __restrict__ rowptr, const int2* __restrict__ ep,
                          const float* __restrict__ ss, const float* __restrict__ sd,
                          const float4* __restrict__ h2v, const float* __restrict__ b,
                          float* __restrict__ out) {
    __shared__ __align__(16) float lds[2][64];
    int n = blockIdx.x;
    int t = threadIdx.x;
    int head = t >> 6, lane = t & 63;
    int q = lane >> 4, r = lane & 15;
    int r0 = rowptr[n], r1 = rowptr[n + 1];
    float sdn = sd[n * 2 + head];
    float a_self = leaky(ss[n * 2 + head] + sdn);
    // pass 1: max, parallel over 64 lanes
    float m = a_self;
    for (int i = r0 + lane; i < r1; i += 64)
        m = fmaxf(m, leaky(ss[ep[i].x * 2 + head] + sdn));
    #pragma unroll
    for (int off = 1; off < 64; off <<= 1)
        m = fmaxf(m, __shfl_xor(m, off, 64));
    // pass 2: expsum + aggregate, 4 edges in flight
    float den = 0.f;
    float4 acc = make_float4(0.f, 0.f, 0.f, 0.f);
    if (q == 0) {
        float exs = __expf(a_self - m);
        den = exs;
        float4 v = h2v[n * 32 + head * 16 + r];
        acc.x = exs * v.x; acc.y = exs * v.y; acc.z = exs * v.z; acc.w = exs * v.w;
    }
    for (int i = r0 + q; i < r1; i += 4) {
        int s = ep[i].x;
        float ex = __expf(leaky(ss[s * 2 + head] + sdn) - m);
        den += ex;
        float4 v = h2v[s * 32 + head * 16 + r];
        acc.x += ex * v.x; acc.y += ex * v.y; acc.z += ex * v.z; acc.w += ex * v.w;
    }
    #pragma unroll
    for (int off = 16; off < 64; off <<= 1) {
        acc.x += __shfl_xor(acc.x, off, 64);
        acc.y += __shfl_xor(acc.y, off, 64);
        acc.z += __shfl_xor(acc.z, off, 64);
        acc.w += __shfl_xor(acc.w, off, 64);
        den   += __shfl_xor(den,   off, 64);
    }
    if (q == 0) {
        float inv = 1.0f / fmaxf(den, 1e-16f);
        *(float4*)&lds[head][r * 4] = make_float4(acc.x * inv, acc.y * inv, acc.z * inv, acc.w * inv);
    }
    __syncthreads();
    if (t < 64) {
        float v = 0.5f * (lds[0][t] + lds[1][t]) + b[t];
        out[n * 64 + t] = fmaxf(v, 0.0f);
    }
}

// ---------------- launch ----------------
extern "C" void kernel_launch(void* const* d_in, const int* in_sizes, int n_in,
                              void* d_out, int out_size, void* d_ws, size_t ws_size,
                              hipStream_t stream) {
    const float* x       = (const float*)d_in[0];
    const int*   eidx    = (const int*)d_in[1];
    const float* ew      = (const float*)d_in[2];
    const float* gcn_w   = (const float*)d_in[3];
    const float* gcn_b   = (const float*)d_in[4];
    const float* gat_w   = (const float*)d_in[5];
    const float* att_src = (const float*)d_in[6];
    const float* att_dst = (const float*)d_in[7];
    const float* gat_b   = (const float*)d_in[8];
    float* out = (float*)d_out;

    const int* src = eidx;            // edge_index[0]
    const int* dst = eidx + N_EDGES;  // edge_index[1]

    // workspace layout: 16B-aligned arrays first
    char* p = (char*)d_ws;
    float* h1      = (float*)p; p += sizeof(float) * (size_t)N_NODES * 64;
    float* agg1    = (float*)p; p += sizeof(float) * (size_t)N_NODES * 64;
    float* h2      = (float*)p; p += sizeof(float) * (size_t)N_NODES * 128;
    int2*  ep      = (int2*)p;  p += sizeof(int2) * (size_t)N_EDGES;
    float* deg     = (float*)p; p += sizeof(float) * N_NODES;        // deg -> dinv in place
    int*   count   = (int*)p;   p += sizeof(int) * N_NODES;
    int*   incl    = (int*)p;   p += sizeof(int) * N_NODES;
    int*   bsum    = (int*)p;   p += sizeof(int) * NB_SCAN;
    int*   boff    = (int*)p;   p += sizeof(int) * NB_SCAN;
    int*   rowptr  = (int*)p;   p += sizeof(int) * (N_NODES + 1);
    int*   cursor  = (int*)p;   p += sizeof(int) * N_NODES;
    float* score_s = (float*)p; p += sizeof(float) * N_NODES * 2;
    float* score_d = (float*)p; p += sizeof(float) * N_NODES * 2;

    const int T = 256;
    const int NBn = (N_NODES + T - 1) / T;
    const int NBe = (N_EDGES + T - 1) / T;

    // CSR build
    k_init<<<NBn, T, 0, stream>>>(count, deg);
    k_count_deg<<<NBe, T, 0, stream>>>(dst, ew, count, deg);
    k_dinv<<<NBn, T, 0, stream>>>(deg);
    k_scan_a<<<NB_SCAN, T, 0, stream>>>(count, incl, bsum);
    k_scan_b<<<1, 512, 0, stream>>>(bsum, boff);
    k_scan_c<<<NB_SCAN, T, 0, stream>>>(count, incl, boff, rowptr, cursor);
    k_scatter<<<NBe, T, 0, stream>>>(src, dst, ew, deg, cursor, ep);

    // layer 1: GCN
    k_gemm1<<<(N_NODES + 63) / 64, T, 0, stream>>>(x, gcn_w, h1);
    k_gcn_csr<<<(N_NODES + 3) / 4, T, 0, stream>>>(rowptr, ep, deg, (const float4*)h1, gcn_b, (float4*)agg1);

    // layer 2: GAT
    k_gemm2<<<((N_NODES + 63) / 64) * 2, T, 0, stream>>>(agg1, gat_w, h2);
    k_scores<<<N_NODES, 128, 0, stream>>>(h2, att_src, att_dst, score_s, score_d);
    k_gat_csr<<<N_NODES, 128, 0, stream>>>(rowptr, ep, score_s, score_d, (const float4*)h2, gat_b, out);
}

// Round 4
// 521.160 us; speedup vs baseline: 3.4652x; 1.2733x over previous
//
#include <hip/hip_runtime.h>
#include <hip/hip_fp16.h>
#include <math.h>

#define N_NODES 100000
#define N_EDGES 1600000
#define IN_CH 128
#define HID 64
#define HEADS 2
#define NEG_SLOPE 0.2f

#define NB_SCAN ((N_NODES + 255) / 256)   // 391 scan blocks
#define FXS 1048576.0f                    // 2^20 fixed-point scale for deg

static __device__ inline ushort f2h(float f) { return __half_as_ushort(__float2half(f)); }
static __device__ inline float h2f(ushort u) { return __half2float(__ushort_as_half(u)); }
static __device__ inline float4 h4f(ushort4 u) {
    return make_float4(h2f(u.x), h2f(u.y), h2f(u.z), h2f(u.w));
}

// ---------------- CSR build ----------------

// cd[n] = {count:0, deg:1.0 fixed-point} (self-loop weight)
__global__ void k_init(unsigned long long* cd) {
    int n = blockIdx.x * 256 + threadIdx.x;
    if (n < N_NODES) cd[n] = (unsigned long long)(unsigned)(FXS);
}

// one packed atomic per edge: count += 1, deg += ew (fixed-point)
__global__ void k_count_deg(const int* __restrict__ dst, const float* __restrict__ ew,
                            unsigned long long* cd) {
    int e = blockIdx.x * 256 + threadIdx.x;
    if (e >= N_EDGES) return;
    unsigned fx = (unsigned)(ew[e] * FXS + 0.5f);
    atomicAdd(&cd[dst[e]], (1ull << 32) | (unsigned long long)fx);
}

__global__ void k_dinv(const unsigned long long* __restrict__ cd, float* dinv) {
    int n = blockIdx.x * 256 + threadIdx.x;
    if (n < N_NODES) dinv[n] = rsqrtf((float)(unsigned)(cd[n] & 0xffffffffu) * (1.0f / FXS));
}

// per-block inclusive scan of counts -> incl, block totals -> bsum
__global__ void k_scan_a(const unsigned long long* __restrict__ cd, int* __restrict__ incl,
                         int* __restrict__ bsum) {
    __shared__ int sh[256];
    int tid = threadIdx.x;
    int g = blockIdx.x * 256 + tid;
    int v = (g < N_NODES) ? (int)(cd[g] >> 32) : 0;
    sh[tid] = v;
    __syncthreads();
    for (int off = 1; off < 256; off <<= 1) {
        int t = (tid >= off) ? sh[tid - off] : 0;
        __syncthreads();
        sh[tid] += t;
        __syncthreads();
    }
    if (g < N_NODES) incl[g] = sh[tid];
    if (tid == 255) bsum[blockIdx.x] = sh[255];
}

__global__ void k_scan_b(const int* __restrict__ bsum, int* __restrict__ boff) {
    __shared__ int sh[512];
    int tid = threadIdx.x;
    int v = (tid < NB_SCAN) ? bsum[tid] : 0;
    sh[tid] = v;
    __syncthreads();
    for (int off = 1; off < 512; off <<= 1) {
        int t = (tid >= off) ? sh[tid - off] : 0;
        __syncthreads();
        sh[tid] += t;
        __syncthreads();
    }
    if (tid < NB_SCAN) boff[tid] = sh[tid] - v;   // exclusive
}

__global__ void k_scan_c(const unsigned long long* __restrict__ cd, const int* __restrict__ incl,
                         const int* __restrict__ boff, int* rowptr, int* cursor) {
    int g = blockIdx.x * 256 + threadIdx.x;
    if (g >= N_NODES) return;
    int excl = incl[g] - (int)(cd[g] >> 32) + boff[blockIdx.x];
    rowptr[g] = excl;
    cursor[g] = excl;
    if (g == N_NODES - 1) rowptr[N_NODES] = incl[g] + boff[blockIdx.x];
}

// scatter edges into CSR order; pack {src, gcn_norm} into int2 (one 8B store)
__global__ void k_scatter(const int* __restrict__ src, const int* __restrict__ dst,
                          const float* __restrict__ ew, const float* __restrict__ dinv,
                          int* cursor, int2* __restrict__ ep) {
    int e = blockIdx.x * 256 + threadIdx.x;
    if (e >= N_EDGES) return;
    int s = src[e], d = dst[e];
    int pos = atomicAdd(&cursor[d], 1);
    float nrm = dinv[s] * ew[e] * dinv[d];
    ep[pos] = make_int2(s, __float_as_int(nrm));
}

// ---------------- dense: register-tiled GEMMs, fp16 outputs ----------------

// h1 = x @ gcn_w   [N,128]@[128,64] -> fp16
__global__ __launch_bounds__(256) void k_gemm1(const float* __restrict__ x,
                                               const float* __restrict__ w,
                                               ushort4* __restrict__ h1h) {
    __shared__ float sxT[128][64];   // [k][r]
    __shared__ float sw[128][64];    // [k][c]
    int t = threadIdx.x;
    int tx = t & 15, ty = t >> 4;
    int row0 = blockIdx.x * 64;
    for (int i = t; i < 128 * 16; i += 256)
        ((float4*)sw)[i] = ((const float4*)w)[i];
    for (int i = t; i < 64 * 32; i += 256) {
        int r = i >> 5, kq = i & 31;
        int row = row0 + r;
        float4 v = make_float4(0.f, 0.f, 0.f, 0.f);
        if (row < N_NODES) v = ((const float4*)x)[row * 32 + kq];
        int k = kq * 4;
        sxT[k][r] = v.x; sxT[k + 1][r] = v.y; sxT[k + 2][r] = v.z; sxT[k + 3][r] = v.w;
    }
    __syncthreads();
    float acc[4][4] = {};
    for (int k = 0; k < 128; ++k) {
        float4 a = *(const float4*)&sxT[k][ty * 4];
        float4 bb = *(const float4*)&sw[k][tx * 4];
        acc[0][0] += a.x * bb.x; acc[0][1] += a.x * bb.y; acc[0][2] += a.x * bb.z; acc[0][3] += a.x * bb.w;
        acc[1][0] += a.y * bb.x; acc[1][1] += a.y * bb.y; acc[1][2] += a.y * bb.z; acc[1][3] += a.y * bb.w;
        acc[2][0] += a.z * bb.x; acc[2][1] += a.z * bb.y; acc[2][2] += a.z * bb.z; acc[2][3] += a.z * bb.w;
        acc[3][0] += a.w * bb.x; acc[3][1] += a.w * bb.y; acc[3][2] += a.w * bb.z; acc[3][3] += a.w * bb.w;
    }
    #pragma unroll
    for (int i = 0; i < 4; ++i) {
        int row = row0 + ty * 4 + i;
        if (row < N_NODES) {
            ushort4 o;
            o.x = f2h(acc[i][0]); o.y = f2h(acc[i][1]); o.z = f2h(acc[i][2]); o.w = f2h(acc[i][3]);
            h1h[row * 16 + tx] = o;   // row stride = 64 halves = 16 ushort4
        }
    }
}

// h2 = agg1 @ gat_w   [N,64]@[64,128] -> fp16; grid = tiles x 2 column halves
__global__ __launch_bounds__(256) void k_gemm2(const float* __restrict__ a,
                                               const float* __restrict__ w,
                                               ushort4* __restrict__ h2h) {
    __shared__ float sxT[64][64];    // [k][r]
    __shared__ float swh[64][64];    // [k][c] (column half)
    int t = threadIdx.x;
    int tx = t & 15, ty = t >> 4;
    int tile = blockIdx.x >> 1, half = blockIdx.x & 1;
    int row0 = tile * 64;
    for (int i = t; i < 64 * 16; i += 256) {
        int k = i >> 4, cq = i & 15;
        float4 v = ((const float4*)(w + k * 128 + half * 64))[cq];
        ((float4*)&swh[k][cq * 4])[0] = v;
    }
    for (int i = t; i < 64 * 16; i += 256) {
        int r = i >> 4, kq = i & 15;
        int row = row0 + r;
        float4 v = make_float4(0.f, 0.f, 0.f, 0.f);
        if (row < N_NODES) v = ((const float4*)a)[row * 16 + kq];
        int k = kq * 4;
        sxT[k][r] = v.x; sxT[k + 1][r] = v.y; sxT[k + 2][r] = v.z; sxT[k + 3][r] = v.w;
    }
    __syncthreads();
    float acc[4][4] = {};
    for (int k = 0; k < 64; ++k) {
        float4 av = *(const float4*)&sxT[k][ty * 4];
        float4 bb = *(const float4*)&swh[k][tx * 4];
        acc[0][0] += av.x * bb.x; acc[0][1] += av.x * bb.y; acc[0][2] += av.x * bb.z; acc[0][3] += av.x * bb.w;
        acc[1][0] += av.y * bb.x; acc[1][1] += av.y * bb.y; acc[1][2] += av.y * bb.z; acc[1][3] += av.y * bb.w;
        acc[2][0] += av.z * bb.x; acc[2][1] += av.z * bb.y; acc[2][2] += av.z * bb.z; acc[2][3] += av.z * bb.w;
        acc[3][0] += av.w * bb.x; acc[3][1] += av.w * bb.y; acc[3][2] += av.w * bb.z; acc[3][3] += av.w * bb.w;
    }
    #pragma unroll
    for (int i = 0; i < 4; ++i) {
        int row = row0 + ty * 4 + i;
        if (row < N_NODES) {
            ushort4 o;
            o.x = f2h(acc[i][0]); o.y = f2h(acc[i][1]); o.z = f2h(acc[i][2]); o.w = f2h(acc[i][3]);
            h2h[row * 32 + half * 16 + tx] = o;   // row stride = 128 halves = 32 ushort4
        }
    }
}

// ---------------- segment gather kernels ----------------

// GCN: wave = node; lanes = 4 edge-groups x 16 (4 fp16 channels each).
__global__ void k_gcn_csr(const int* __restrict__ rowptr, const int2* __restrict__ ep,
                          const float* __restrict__ dinv, const ushort4* __restrict__ h1h,
                          const float* __restrict__ b, float4* __restrict__ agg1v) {
    int t = threadIdx.x;
    int n = blockIdx.x * 4 + (t >> 6);
    if (n >= N_NODES) return;
    int lane = t & 63, q = lane >> 4, r = lane & 15;
    int r0 = rowptr[n], r1 = rowptr[n + 1];
    float4 acc = make_float4(0.f, 0.f, 0.f, 0.f);
    if (q == 0) {
        float di = dinv[n];
        float wl = di * di;
        float4 v = h4f(h1h[n * 16 + r]);
        acc.x = wl * v.x; acc.y = wl * v.y; acc.z = wl * v.z; acc.w = wl * v.w;
    }
    for (int i = r0 + q; i < r1; i += 4) {
        int2 e = ep[i];
        float wl = __int_as_float(e.y);
        float4 v = h4f(h1h[e.x * 16 + r]);
        acc.x += wl * v.x; acc.y += wl * v.y; acc.z += wl * v.z; acc.w += wl * v.w;
    }
    #pragma unroll
    for (int off = 16; off < 64; off <<= 1) {
        acc.x += __shfl_xor(acc.x, off, 64);
        acc.y += __shfl_xor(acc.y, off, 64);
        acc.z += __shfl_xor(acc.z, off, 64);
        acc.w += __shfl_xor(acc.w, off, 64);
    }
    if (q == 0) {
        float4 bb = ((const float4*)b)[r];
        agg1v[n * 16 + r] = make_float4(fmaxf(acc.x + bb.x, 0.f), fmaxf(acc.y + bb.y, 0.f),
                                        fmaxf(acc.z + bb.z, 0.f), fmaxf(acc.w + bb.w, 0.f));
    }
}

// attention scores: wave = node; lane covers 2 channels (fp16 pair); half-wave = head.
__global__ void k_scores(const ushort2* __restrict__ h2h2, const float* __restrict__ a_src,
                         const float* __restrict__ a_dst,
                         float* __restrict__ ss, float* __restrict__ sd) {
    int t = threadIdx.x;
    int n = blockIdx.x * 4 + (t >> 6);
    if (n >= N_NODES) return;
    int lane = t & 63;                 // channel pair 2*lane, 2*lane+1; head = lane>>5
    ushort2 u = h2h2[n * 64 + lane];
    float hx = h2f(u.x), hy = h2f(u.y);
    float ps = hx * a_src[2 * lane] + hy * a_src[2 * lane + 1];
    float pd = hx * a_dst[2 * lane] + hy * a_dst[2 * lane + 1];
    #pragma unroll
    for (int off = 1; off < 32; off <<= 1) {   // reduce within each 32-lane half
        ps += __shfl_xor(ps, off, 64);
        pd += __shfl_xor(pd, off, 64);
    }
    if ((lane & 31) == 0) {
        int h = lane >> 5;
        ss[n * 2 + h] = ps;
        sd[n * 2 + h] = pd;
    }
}

__device__ inline float leaky(float a) { return (a >= 0.0f) ? a : NEG_SLOPE * a; }

// GAT: block=128 -> 1 node; wave = head; lanes = 4 edge-groups x 16 (4 fp16 ch each).
// No max pass: scores are O(+-3), exp(alpha) cannot overflow fp32; softmax shift-invariant.
__global__ void k_gat_csr(const int* __restrict__ rowptr, const int2* __restrict__ ep,
                          const float* __restrict__ ss, const float* __restrict__ sd,
                          const ushort4* __restrict__ h2h, const float* __restrict__ b,
                          float* __restrict__ out) {
    __shared__ __align__(16) float lds[2][64];
    int n = blockIdx.x;
    int t = threadIdx.x;
    int head = t >> 6, lane = t & 63;
    int q = lane >> 4, r = lane & 15;
    int r0 = rowptr[n], r1 = rowptr[n + 1];
    float sdn = sd[n * 2 + head];
    float den = 0.f;
    float4 acc = make_float4(0.f, 0.f, 0.f, 0.f);
    if (q == 0) {
        float exs = __expf(leaky(ss[n * 2 + head] + sdn));
        den = exs;
        float4 v = h4f(h2h[n * 32 + head * 16 + r]);
        acc.x = exs * v.x; acc.y = exs * v.y; acc.z = exs * v.z; acc.w = exs * v.w;
    }
    for (int i = r0 + q; i < r1; i += 4) {
        int s = ep[i].x;
        float ex = __expf(leaky(ss[s * 2 + head] + sdn));
        den += ex;
        float4 v = h4f(h2h[s * 32 + head * 16 + r]);
        acc.x += ex * v.x; acc.y += ex * v.y; acc.z += ex * v.z; acc.w += ex * v.w;
    }
    #pragma unroll
    for (int off = 16; off < 64; off <<= 1) {   // sum across the 4 edge-groups
        acc.x += __shfl_xor(acc.x, off, 64);
        acc.y += __shfl_xor(acc.y, off, 64);
        acc.z += __shfl_xor(acc.z, off, 64);
        acc.w += __shfl_xor(acc.w, off, 64);
        den   += __shfl_xor(den,   off, 64);
    }
    if (q == 0) {
        float inv = 1.0f / fmaxf(den, 1e-16f);
        *(float4*)&lds[head][r * 4] = make_float4(acc.x * inv, acc.y * inv, acc.z * inv, acc.w * inv);
    }
    __syncthreads();
    if (t < 64) {
        float v = 0.5f * (lds[0][t] + lds[1][t]) + b[t];
        out[n * 64 + t] = fmaxf(v, 0.0f);
    }
}

// ---------------- launch ----------------
extern "C" void kernel_launch(void* const* d_in, const int* in_sizes, int n_in,
                              void* d_out, int out_size, void* d_ws, size_t ws_size,
                              hipStream_t stream) {
    const float* x       = (const float*)d_in[0];
    const int*   eidx    = (const int*)d_in[1];
    const float* ew      = (const float*)d_in[2];
    const float* gcn_w   = (const float*)d_in[3];
    const float* gcn_b   = (const float*)d_in[4];
    const float* gat_w   = (const float*)d_in[5];
    const float* att_src = (const float*)d_in[6];
    const float* att_dst = (const float*)d_in[7];
    const float* gat_b   = (const float*)d_in[8];
    float* out = (float*)d_out;

    const int* src = eidx;            // edge_index[0]
    const int* dst = eidx + N_EDGES;  // edge_index[1]

    // workspace layout (16B-aligned blocks first)
    char* p = (char*)d_ws;
    float* agg1   = (float*)p;  p += sizeof(float) * (size_t)N_NODES * 64;    // fp32 gemm2 input
    ushort* h1h   = (ushort*)p; p += sizeof(ushort) * (size_t)N_NODES * 64;   // fp16
    ushort* h2h   = (ushort*)p; p += sizeof(ushort) * (size_t)N_NODES * 128;  // fp16
    int2*  ep     = (int2*)p;   p += sizeof(int2) * (size_t)N_EDGES;
    unsigned long long* cd = (unsigned long long*)p; p += sizeof(unsigned long long) * N_NODES;
    float* dinv   = (float*)p;  p += sizeof(float) * N_NODES;
    int*   incl   = (int*)p;    p += sizeof(int) * N_NODES;
    int*   rowptr = (int*)p;    p += sizeof(int) * (N_NODES + 1);
    int*   cursor = (int*)p;    p += sizeof(int) * N_NODES;
    float* ss     = (float*)p;  p += sizeof(float) * N_NODES * 2;
    float* sd     = (float*)p;  p += sizeof(float) * N_NODES * 2;
    int*   bsum   = (int*)p;    p += sizeof(int) * NB_SCAN;
    int*   boff   = (int*)p;    p += sizeof(int) * NB_SCAN;

    const int T = 256;
    const int NBn = (N_NODES + T - 1) / T;
    const int NBe = (N_EDGES + T - 1) / T;

    // CSR build
    k_init<<<NBn, T, 0, stream>>>(cd);
    k_count_deg<<<NBe, T, 0, stream>>>(dst, ew, cd);
    k_dinv<<<NBn, T, 0, stream>>>(cd, dinv);
    k_scan_a<<<NB_SCAN, T, 0, stream>>>(cd, incl, bsum);
    k_scan_b<<<1, 512, 0, stream>>>(bsum, boff);
    k_scan_c<<<NB_SCAN, T, 0, stream>>>(cd, incl, boff, rowptr, cursor);
    k_scatter<<<NBe, T, 0, stream>>>(src, dst, ew, dinv, cursor, ep);

    // layer 1: GCN
    k_gemm1<<<(N_NODES + 63) / 64, T, 0, stream>>>(x, gcn_w, (ushort4*)h1h);
    k_gcn_csr<<<(N_NODES + 3) / 4, T, 0, stream>>>(rowptr, ep, dinv, (const ushort4*)h1h, gcn_b, (float4*)agg1);

    // layer 2: GAT
    k_gemm2<<<((N_NODES + 63) / 64) * 2, T, 0, stream>>>(agg1, gat_w, (ushort4*)h2h);
    k_scores<<<(N_NODES + 3) / 4, T, 0, stream>>>((const ushort2*)h2h, att_src, att_dst, ss, sd);
    k_gat_csr<<<N_NODES, 128, 0, stream>>>(rowptr, ep, ss, sd, (const ushort4*)h2h, gat_b, out);
}

// Round 5
// 493.471 us; speedup vs baseline: 3.6597x; 1.0561x over previous
//
#include <hip/hip_runtime.h>
#include <hip/hip_fp16.h>
#include <math.h>

#define N_NODES 100000
#define N_EDGES 1600000
#define IN_CH 128
#define HID 64
#define HEADS 2
#define NEG_SLOPE 0.2f

#define NB_SCAN ((N_NODES + 255) / 256)   // 391 scan blocks
#define FXS 1048576.0f                    // 2^20 fixed-point scale for deg

static __device__ inline ushort f2h(float f) { return __half_as_ushort(__float2half(f)); }
static __device__ inline float h2f(ushort u) { return __half2float(__ushort_as_half(u)); }
static __device__ inline void h8f(uint4 u, float f[8]) {
    f[0] = h2f((ushort)(u.x & 0xffff)); f[1] = h2f((ushort)(u.x >> 16));
    f[2] = h2f((ushort)(u.y & 0xffff)); f[3] = h2f((ushort)(u.y >> 16));
    f[4] = h2f((ushort)(u.z & 0xffff)); f[5] = h2f((ushort)(u.z >> 16));
    f[6] = h2f((ushort)(u.w & 0xffff)); f[7] = h2f((ushort)(u.w >> 16));
}

__device__ inline float leaky(float a) { return (a >= 0.0f) ? a : NEG_SLOPE * a; }

// ---------------- CSR build ----------------

// cd[n] = {count:0, deg:1.0 fixed-point} (self-loop weight)
__global__ void k_init(unsigned long long* cd) {
    int n = blockIdx.x * 256 + threadIdx.x;
    if (n < N_NODES) cd[n] = (unsigned long long)(unsigned)(FXS);
}

// one packed atomic per edge: count += 1, deg += ew (fixed-point)
__global__ void k_count_deg(const int* __restrict__ dst, const float* __restrict__ ew,
                            unsigned long long* cd) {
    int e = blockIdx.x * 256 + threadIdx.x;
    if (e >= N_EDGES) return;
    unsigned fx = (unsigned)(ew[e] * FXS + 0.5f);
    atomicAdd(&cd[dst[e]], (1ull << 32) | (unsigned long long)fx);
}

// per-block inclusive scan of counts -> incl, block totals -> bsum; also dinv = deg^{-1/2}
__global__ void k_scan_a(const unsigned long long* __restrict__ cd, int* __restrict__ incl,
                         int* __restrict__ bsum, float* __restrict__ dinv) {
    __shared__ int sh[256];
    int tid = threadIdx.x;
    int g = blockIdx.x * 256 + tid;
    unsigned long long c = (g < N_NODES) ? cd[g] : 0ull;
    int v = (int)(c >> 32);
    if (g < N_NODES) dinv[g] = rsqrtf((float)(unsigned)(c & 0xffffffffu) * (1.0f / FXS));
    sh[tid] = v;
    __syncthreads();
    for (int off = 1; off < 256; off <<= 1) {
        int t = (tid >= off) ? sh[tid - off] : 0;
        __syncthreads();
        sh[tid] += t;
        __syncthreads();
    }
    if (g < N_NODES) incl[g] = sh[tid];
    if (tid == 255) bsum[blockIdx.x] = sh[255];
}

__global__ void k_scan_b(const int* __restrict__ bsum, int* __restrict__ boff) {
    __shared__ int sh[512];
    int tid = threadIdx.x;
    int v = (tid < NB_SCAN) ? bsum[tid] : 0;
    sh[tid] = v;
    __syncthreads();
    for (int off = 1; off < 512; off <<= 1) {
        int t = (tid >= off) ? sh[tid - off] : 0;
        __syncthreads();
        sh[tid] += t;
        __syncthreads();
    }
    if (tid < NB_SCAN) boff[tid] = sh[tid] - v;   // exclusive
}

__global__ void k_scan_c(const unsigned long long* __restrict__ cd, const int* __restrict__ incl,
                         const int* __restrict__ boff, int* rowptr, int* cursor) {
    int g = blockIdx.x * 256 + threadIdx.x;
    if (g >= N_NODES) return;
    int excl = incl[g] - (int)(cd[g] >> 32) + boff[blockIdx.x];
    rowptr[g] = excl;
    cursor[g] = excl;
    if (g == N_NODES - 1) rowptr[N_NODES] = incl[g] + boff[blockIdx.x];
}

// scatter edges into CSR order (split arrays: es = src only for GAT, enrm for GCN)
__global__ void k_scatter(const int* __restrict__ src, const int* __restrict__ dst,
                          const float* __restrict__ ew, const float* __restrict__ dinv,
                          int* cursor, int* __restrict__ es, float* __restrict__ enrm) {
    int e = blockIdx.x * 256 + threadIdx.x;
    if (e >= N_EDGES) return;
    int s = src[e], d = dst[e];
    int pos = atomicAdd(&cursor[d], 1);
    es[pos] = s;
    enrm[pos] = dinv[s] * ew[e] * dinv[d];
}

// ---------------- dense: register-tiled GEMMs, fp16 outputs ----------------

// h1 = x @ gcn_w   [N,128]@[128,64] -> fp16
__global__ __launch_bounds__(256) void k_gemm1(const float* __restrict__ x,
                                               const float* __restrict__ w,
                                               ushort4* __restrict__ h1h) {
    __shared__ float sxT[128][64];   // [k][r]
    __shared__ float sw[128][64];    // [k][c]
    int t = threadIdx.x;
    int tx = t & 15, ty = t >> 4;
    int row0 = blockIdx.x * 64;
    for (int i = t; i < 128 * 16; i += 256)
        ((float4*)sw)[i] = ((const float4*)w)[i];
    for (int i = t; i < 64 * 32; i += 256) {
        int r = i >> 5, kq = i & 31;
        int row = row0 + r;
        float4 v = make_float4(0.f, 0.f, 0.f, 0.f);
        if (row < N_NODES) v = ((const float4*)x)[row * 32 + kq];
        int k = kq * 4;
        sxT[k][r] = v.x; sxT[k + 1][r] = v.y; sxT[k + 2][r] = v.z; sxT[k + 3][r] = v.w;
    }
    __syncthreads();
    float acc[4][4] = {};
    for (int k = 0; k < 128; ++k) {
        float4 a = *(const float4*)&sxT[k][ty * 4];
        float4 bb = *(const float4*)&sw[k][tx * 4];
        acc[0][0] += a.x * bb.x; acc[0][1] += a.x * bb.y; acc[0][2] += a.x * bb.z; acc[0][3] += a.x * bb.w;
        acc[1][0] += a.y * bb.x; acc[1][1] += a.y * bb.y; acc[1][2] += a.y * bb.z; acc[1][3] += a.y * bb.w;
        acc[2][0] += a.z * bb.x; acc[2][1] += a.z * bb.y; acc[2][2] += a.z * bb.z; acc[2][3] += a.z * bb.w;
        acc[3][0] += a.w * bb.x; acc[3][1] += a.w * bb.y; acc[3][2] += a.w * bb.z; acc[3][3] += a.w * bb.w;
    }
    #pragma unroll
    for (int i = 0; i < 4; ++i) {
        int row = row0 + ty * 4 + i;
        if (row < N_NODES) {
            ushort4 o;
            o.x = f2h(acc[i][0]); o.y = f2h(acc[i][1]); o.z = f2h(acc[i][2]); o.w = f2h(acc[i][3]);
            h1h[row * 16 + tx] = o;   // row stride = 64 halves = 16 ushort4
        }
    }
}

// h2 = agg1 @ gat_w [N,64]@[64,128] -> fp16; grid = tiles x 2 column halves.
// half == head: fused attention scores ss/sd computed from fp32 acc in epilogue.
__global__ __launch_bounds__(256) void k_gemm2(const float* __restrict__ a,
                                               const float* __restrict__ w,
                                               const float* __restrict__ att_src,
                                               const float* __restrict__ att_dst,
                                               ushort4* __restrict__ h2h,
                                               float* __restrict__ ss, float* __restrict__ sd) {
    __shared__ float sxT[64][64];    // [k][r]
    __shared__ float swh[64][64];    // [k][c] (column half)
    int t = threadIdx.x;
    int tx = t & 15, ty = t >> 4;
    int tile = blockIdx.x >> 1, half = blockIdx.x & 1;
    int row0 = tile * 64;
    for (int i = t; i < 64 * 16; i += 256) {
        int k = i >> 4, cq = i & 15;
        float4 v = ((const float4*)(w + k * 128 + half * 64))[cq];
        ((float4*)&swh[k][cq * 4])[0] = v;
    }
    for (int i = t; i < 64 * 16; i += 256) {
        int r = i >> 4, kq = i & 15;
        int row = row0 + r;
        float4 v = make_float4(0.f, 0.f, 0.f, 0.f);
        if (row < N_NODES) v = ((const float4*)a)[row * 16 + kq];
        int k = kq * 4;
        sxT[k][r] = v.x; sxT[k + 1][r] = v.y; sxT[k + 2][r] = v.z; sxT[k + 3][r] = v.w;
    }
    __syncthreads();
    float acc[4][4] = {};
    for (int k = 0; k < 64; ++k) {
        float4 av = *(const float4*)&sxT[k][ty * 4];
        float4 bb = *(const float4*)&swh[k][tx * 4];
        acc[0][0] += av.x * bb.x; acc[0][1] += av.x * bb.y; acc[0][2] += av.x * bb.z; acc[0][3] += av.x * bb.w;
        acc[1][0] += av.y * bb.x; acc[1][1] += av.y * bb.y; acc[1][2] += av.y * bb.z; acc[1][3] += av.y * bb.w;
        acc[2][0] += av.z * bb.x; acc[2][1] += av.z * bb.y; acc[2][2] += av.z * bb.z; acc[2][3] += av.z * bb.w;
        acc[3][0] += av.w * bb.x; acc[3][1] += av.w * bb.y; acc[3][2] += av.w * bb.z; acc[3][3] += av.w * bb.w;
    }
    float as0 = att_src[half * 64 + tx * 4],     as1 = att_src[half * 64 + tx * 4 + 1];
    float as2 = att_src[half * 64 + tx * 4 + 2], as3 = att_src[half * 64 + tx * 4 + 3];
    float ad0 = att_dst[half * 64 + tx * 4],     ad1 = att_dst[half * 64 + tx * 4 + 1];
    float ad2 = att_dst[half * 64 + tx * 4 + 2], ad3 = att_dst[half * 64 + tx * 4 + 3];
    #pragma unroll
    for (int i = 0; i < 4; ++i) {
        int row = row0 + ty * 4 + i;
        float ps = acc[i][0] * as0 + acc[i][1] * as1 + acc[i][2] * as2 + acc[i][3] * as3;
        float pd = acc[i][0] * ad0 + acc[i][1] * ad1 + acc[i][2] * ad2 + acc[i][3] * ad3;
        #pragma unroll
        for (int off = 1; off < 16; off <<= 1) {   // reduce over 16 lanes sharing this row
            ps += __shfl_xor(ps, off, 64);
            pd += __shfl_xor(pd, off, 64);
        }
        if (row < N_NODES) {
            if (tx == 0) { ss[row * 2 + half] = ps; sd[row * 2 + half] = pd; }
            ushort4 o;
            o.x = f2h(acc[i][0]); o.y = f2h(acc[i][1]); o.z = f2h(acc[i][2]); o.w = f2h(acc[i][3]);
            h2h[row * 32 + half * 16 + tx] = o;   // row stride = 128 halves = 32 ushort4
        }
    }
}

// ---------------- segment gather kernels ----------------

// GCN: wave = node; lanes = 8 edge-groups x 8 (8 fp16 channels via uint4).
__global__ void k_gcn_csr(const int* __restrict__ rowptr, const int* __restrict__ es,
                          const float* __restrict__ enrm, const float* __restrict__ dinv,
                          const uint4* __restrict__ h1q, const float* __restrict__ b,
                          float4* __restrict__ agg1v) {
    int t = threadIdx.x;
    int n = blockIdx.x * 4 + (t >> 6);
    if (n >= N_NODES) return;
    int lane = t & 63, q = lane >> 3, r = lane & 7;
    int r0 = rowptr[n], r1 = rowptr[n + 1];
    float acc[8] = {};
    if (q == 0) {
        float di = dinv[n];
        float wl = di * di;
        float f[8]; h8f(h1q[n * 8 + r], f);
        #pragma unroll
        for (int j = 0; j < 8; ++j) acc[j] = wl * f[j];
    }
    for (int i = r0 + q; i < r1; i += 8) {
        int s = es[i];
        float wl = enrm[i];
        float f[8]; h8f(h1q[s * 8 + r], f);
        #pragma unroll
        for (int j = 0; j < 8; ++j) acc[j] += wl * f[j];
    }
    #pragma unroll
    for (int off = 8; off < 64; off <<= 1) {
        #pragma unroll
        for (int j = 0; j < 8; ++j) acc[j] += __shfl_xor(acc[j], off, 64);
    }
    if (q == 0) {
        float4 b0 = ((const float4*)b)[2 * r], b1 = ((const float4*)b)[2 * r + 1];
        agg1v[n * 16 + 2 * r] = make_float4(fmaxf(acc[0] + b0.x, 0.f), fmaxf(acc[1] + b0.y, 0.f),
                                            fmaxf(acc[2] + b0.z, 0.f), fmaxf(acc[3] + b0.w, 0.f));
        agg1v[n * 16 + 2 * r + 1] = make_float4(fmaxf(acc[4] + b1.x, 0.f), fmaxf(acc[5] + b1.y, 0.f),
                                                fmaxf(acc[6] + b1.z, 0.f), fmaxf(acc[7] + b1.w, 0.f));
    }
}

// GAT: block=128 -> 1 node; wave = head; lanes = 8 edge-groups x 8 (8 fp16 ch via uint4).
// No max pass: scores are O(+-few), exp cannot overflow fp32; softmax shift-invariant.
__global__ void k_gat_csr(const int* __restrict__ rowptr, const int* __restrict__ es,
                          const float* __restrict__ ss, const float* __restrict__ sd,
                          const uint4* __restrict__ h2q, const float* __restrict__ b,
                          float* __restrict__ out) {
    __shared__ __align__(16) float lds[2][64];
    int n = blockIdx.x;
    int t = threadIdx.x;
    int head = t >> 6, lane = t & 63;
    int q = lane >> 3, r = lane & 7;
    int r0 = rowptr[n], r1 = rowptr[n + 1];
    float sdn = sd[n * 2 + head];
    float den = 0.f;
    float acc[8] = {};
    if (q == 0) {
        float exs = __expf(leaky(ss[n * 2 + head] + sdn));
        den = exs;
        float f[8]; h8f(h2q[n * 16 + head * 8 + r], f);
        #pragma unroll
        for (int j = 0; j < 8; ++j) acc[j] = exs * f[j];
    }
    for (int i = r0 + q; i < r1; i += 8) {
        int s = es[i];
        float ex = __expf(leaky(ss[s * 2 + head] + sdn));
        den += ex;
        float f[8]; h8f(h2q[s * 16 + head * 8 + r], f);
        #pragma unroll
        for (int j = 0; j < 8; ++j) acc[j] += ex * f[j];
    }
    #pragma unroll
    for (int off = 8; off < 64; off <<= 1) {
        #pragma unroll
        for (int j = 0; j < 8; ++j) acc[j] += __shfl_xor(acc[j], off, 64);
        den += __shfl_xor(den, off, 64);
    }
    if (q == 0) {
        float inv = 1.0f / fmaxf(den, 1e-16f);
        *(float4*)&lds[head][r * 8]     = make_float4(acc[0] * inv, acc[1] * inv, acc[2] * inv, acc[3] * inv);
        *(float4*)&lds[head][r * 8 + 4] = make_float4(acc[4] * inv, acc[5] * inv, acc[6] * inv, acc[7] * inv);
    }
    __syncthreads();
    if (t < 64) {
        float v = 0.5f * (lds[0][t] + lds[1][t]) + b[t];
        out[n * 64 + t] = fmaxf(v, 0.0f);
    }
}

// ---------------- launch ----------------
extern "C" void kernel_launch(void* const* d_in, const int* in_sizes, int n_in,
                              void* d_out, int out_size, void* d_ws, size_t ws_size,
                              hipStream_t stream) {
    const float* x       = (const float*)d_in[0];
    const int*   eidx    = (const int*)d_in[1];
    const float* ew      = (const float*)d_in[2];
    const float* gcn_w   = (const float*)d_in[3];
    const float* gcn_b   = (const float*)d_in[4];
    const float* gat_w   = (const float*)d_in[5];
    const float* att_src = (const float*)d_in[6];
    const float* att_dst = (const float*)d_in[7];
    const float* gat_b   = (const float*)d_in[8];
    float* out = (float*)d_out;

    const int* src = eidx;            // edge_index[0]
    const int* dst = eidx + N_EDGES;  // edge_index[1]

    // workspace layout (16B-aligned blocks first)
    char* p = (char*)d_ws;
    float* agg1   = (float*)p;  p += sizeof(float) * (size_t)N_NODES * 64;    // fp32 gemm2 input
    ushort* h1h   = (ushort*)p; p += sizeof(ushort) * (size_t)N_NODES * 64;   // fp16
    ushort* h2h   = (ushort*)p; p += sizeof(ushort) * (size_t)N_NODES * 128;  // fp16
    int*   es     = (int*)p;    p += sizeof(int) * (size_t)N_EDGES;
    float* enrm   = (float*)p;  p += sizeof(float) * (size_t)N_EDGES;
    unsigned long long* cd = (unsigned long long*)p; p += sizeof(unsigned long long) * N_NODES;
    float* dinv   = (float*)p;  p += sizeof(float) * N_NODES;
    int*   incl   = (int*)p;    p += sizeof(int) * N_NODES;
    int*   rowptr = (int*)p;    p += sizeof(int) * (N_NODES + 1);
    int*   cursor = (int*)p;    p += sizeof(int) * N_NODES;
    float* ss     = (float*)p;  p += sizeof(float) * N_NODES * 2;
    float* sd     = (float*)p;  p += sizeof(float) * N_NODES * 2;
    int*   bsum   = (int*)p;    p += sizeof(int) * NB_SCAN;
    int*   boff   = (int*)p;    p += sizeof(int) * NB_SCAN;

    const int T = 256;
    const int NBn = (N_NODES + T - 1) / T;
    const int NBe = (N_EDGES + T - 1) / T;

    // CSR build
    k_init<<<NBn, T, 0, stream>>>(cd);
    k_count_deg<<<NBe, T, 0, stream>>>(dst, ew, cd);
    k_scan_a<<<NB_SCAN, T, 0, stream>>>(cd, incl, bsum, dinv);
    k_scan_b<<<1, 512, 0, stream>>>(bsum, boff);
    k_scan_c<<<NB_SCAN, T, 0, stream>>>(cd, incl, boff, rowptr, cursor);
    k_scatter<<<NBe, T, 0, stream>>>(src, dst, ew, dinv, cursor, es, enrm);

    // layer 1: GCN
    k_gemm1<<<(N_NODES + 63) / 64, T, 0, stream>>>(x, gcn_w, (ushort4*)h1h);
    k_gcn_csr<<<(N_NODES + 3) / 4, T, 0, stream>>>(rowptr, es, enrm, dinv, (const uint4*)h1h, gcn_b, (float4*)agg1);

    // layer 2: GAT (scores fused into gemm2 epilogue)
    k_gemm2<<<((N_NODES + 63) / 64) * 2, T, 0, stream>>>(agg1, gat_w, att_src, att_dst, (ushort4*)h2h, ss, sd);
    k_gat_csr<<<N_NODES, 128, 0, stream>>>(rowptr, es, ss, sd, (const uint4*)h2h, gat_b, out);
}

// Round 6
// 476.134 us; speedup vs baseline: 3.7929x; 1.0364x over previous
//
#include <hip/hip_runtime.h>
#include <hip/hip_fp16.h>
#include <math.h>

#define N_NODES 100000
#define N_EDGES 1600000
#define IN_CH 128
#define HID 64
#define HEADS 2
#define NEG_SLOPE 0.2f

#define NB_SCAN ((N_NODES + 255) / 256)   // 391 scan blocks
#define SHARD_SZ 12500                    // 100000 / 8 XCD shards

static __device__ inline ushort f2h(float f) { return __half_as_ushort(__float2half(f)); }
static __device__ inline float h2f(ushort u) { return __half2float(__ushort_as_half(u)); }
static __device__ inline void h8f(uint4 u, float f[8]) {
    f[0] = h2f((ushort)(u.x & 0xffff)); f[1] = h2f((ushort)(u.x >> 16));
    f[2] = h2f((ushort)(u.y & 0xffff)); f[3] = h2f((ushort)(u.y >> 16));
    f[4] = h2f((ushort)(u.z & 0xffff)); f[5] = h2f((ushort)(u.z >> 16));
    f[6] = h2f((ushort)(u.w & 0xffff)); f[7] = h2f((ushort)(u.w >> 16));
}

__device__ inline float leaky(float a) { return (a >= 0.0f) ? a : NEG_SLOPE * a; }

// ---------------- CSR build (XCD-sharded: blockIdx&7 ~ XCD via round-robin dispatch) ----

// histogram by dst, sharded so each node's counter is only touched from one XCD
__global__ void k_count(const int* __restrict__ dst, int* count) {
    int shard = blockIdx.x & 7;
    int e = (blockIdx.x >> 3) * 256 + threadIdx.x;
    if (e >= N_EDGES) return;
    int d = dst[e];
    if (d / SHARD_SZ != shard) return;
    atomicAdd(&count[d], 1);
}

// per-block inclusive scan of counts -> incl, block totals -> bsum
__global__ void k_scan_a(const int* __restrict__ count, int* __restrict__ incl,
                         int* __restrict__ bsum) {
    __shared__ int sh[256];
    int tid = threadIdx.x;
    int g = blockIdx.x * 256 + tid;
    int v = (g < N_NODES) ? count[g] : 0;
    sh[tid] = v;
    __syncthreads();
    for (int off = 1; off < 256; off <<= 1) {
        int t = (tid >= off) ? sh[tid - off] : 0;
        __syncthreads();
        sh[tid] += t;
        __syncthreads();
    }
    if (g < N_NODES) incl[g] = sh[tid];
    if (tid == 255) bsum[blockIdx.x] = sh[255];
}

__global__ void k_scan_b(const int* __restrict__ bsum, int* __restrict__ boff) {
    __shared__ int sh[512];
    int tid = threadIdx.x;
    int v = (tid < NB_SCAN) ? bsum[tid] : 0;
    sh[tid] = v;
    __syncthreads();
    for (int off = 1; off < 512; off <<= 1) {
        int t = (tid >= off) ? sh[tid - off] : 0;
        __syncthreads();
        sh[tid] += t;
        __syncthreads();
    }
    if (tid < NB_SCAN) boff[tid] = sh[tid] - v;   // exclusive
}

__global__ void k_scan_c(const int* __restrict__ count, const int* __restrict__ incl,
                         const int* __restrict__ boff, int* rowptr, int* cursor) {
    int g = blockIdx.x * 256 + threadIdx.x;
    if (g >= N_NODES) return;
    int excl = incl[g] - count[g] + boff[blockIdx.x];
    rowptr[g] = excl;
    cursor[g] = excl;
    if (g == N_NODES - 1) rowptr[N_NODES] = incl[g] + boff[blockIdx.x];
}

// sharded scatter: one 8B store {src, raw ew} per edge; writes + cursor atomics XCD-local
__global__ void k_scatter(const int* __restrict__ src, const int* __restrict__ dst,
                          const float* __restrict__ ew,
                          int* cursor, int2* __restrict__ ep) {
    int shard = blockIdx.x & 7;
    int e = (blockIdx.x >> 3) * 256 + threadIdx.x;
    if (e >= N_EDGES) return;
    int d = dst[e];
    if (d / SHARD_SZ != shard) return;
    int pos = atomicAdd(&cursor[d], 1);
    ep[pos] = make_int2(src[e], __float_as_int(ew[e]));
}

// deg/dinv from CSR: coalesced sequential reads, no atomics. deg = 1 (self-loop) + sum ew.
__global__ void k_deg_dinv(const int* __restrict__ rowptr, const int2* __restrict__ ep,
                           float* __restrict__ dinv) {
    int n = blockIdx.x * 256 + threadIdx.x;
    if (n >= N_NODES) return;
    int r0 = rowptr[n], r1 = rowptr[n + 1];
    float deg = 1.0f;
    for (int i = r0; i < r1; ++i) deg += __int_as_float(ep[i].y);
    dinv[n] = rsqrtf(deg);
}

// ---------------- dense: register-tiled GEMMs, fp16 outputs ----------------

// h1 = x @ gcn_w   [N,128]@[128,64] -> fp16
__global__ __launch_bounds__(256) void k_gemm1(const float* __restrict__ x,
                                               const float* __restrict__ w,
                                               ushort4* __restrict__ h1h) {
    __shared__ float sxT[128][64];   // [k][r]
    __shared__ float sw[128][64];    // [k][c]
    int t = threadIdx.x;
    int tx = t & 15, ty = t >> 4;
    int row0 = blockIdx.x * 64;
    for (int i = t; i < 128 * 16; i += 256)
        ((float4*)sw)[i] = ((const float4*)w)[i];
    for (int i = t; i < 64 * 32; i += 256) {
        int r = i >> 5, kq = i & 31;
        int row = row0 + r;
        float4 v = make_float4(0.f, 0.f, 0.f, 0.f);
        if (row < N_NODES) v = ((const float4*)x)[row * 32 + kq];
        int k = kq * 4;
        sxT[k][r] = v.x; sxT[k + 1][r] = v.y; sxT[k + 2][r] = v.z; sxT[k + 3][r] = v.w;
    }
    __syncthreads();
    float acc[4][4] = {};
    for (int k = 0; k < 128; ++k) {
        float4 a = *(const float4*)&sxT[k][ty * 4];
        float4 bb = *(const float4*)&sw[k][tx * 4];
        acc[0][0] += a.x * bb.x; acc[0][1] += a.x * bb.y; acc[0][2] += a.x * bb.z; acc[0][3] += a.x * bb.w;
        acc[1][0] += a.y * bb.x; acc[1][1] += a.y * bb.y; acc[1][2] += a.y * bb.z; acc[1][3] += a.y * bb.w;
        acc[2][0] += a.z * bb.x; acc[2][1] += a.z * bb.y; acc[2][2] += a.z * bb.z; acc[2][3] += a.z * bb.w;
        acc[3][0] += a.w * bb.x; acc[3][1] += a.w * bb.y; acc[3][2] += a.w * bb.z; acc[3][3] += a.w * bb.w;
    }
    #pragma unroll
    for (int i = 0; i < 4; ++i) {
        int row = row0 + ty * 4 + i;
        if (row < N_NODES) {
            ushort4 o;
            o.x = f2h(acc[i][0]); o.y = f2h(acc[i][1]); o.z = f2h(acc[i][2]); o.w = f2h(acc[i][3]);
            h1h[row * 16 + tx] = o;   // row stride = 64 halves = 16 ushort4
        }
    }
}

// h2 = agg1 @ gat_w [N,64]@[64,128] -> fp16; grid = tiles x 2 column halves.
// half == head: fused attention scores ss/sd computed from fp32 acc in epilogue.
__global__ __launch_bounds__(256) void k_gemm2(const float* __restrict__ a,
                                               const float* __restrict__ w,
                                               const float* __restrict__ att_src,
                                               const float* __restrict__ att_dst,
                                               ushort4* __restrict__ h2h,
                                               float* __restrict__ ss, float* __restrict__ sd) {
    __shared__ float sxT[64][64];    // [k][r]
    __shared__ float swh[64][64];    // [k][c] (column half)
    int t = threadIdx.x;
    int tx = t & 15, ty = t >> 4;
    int tile = blockIdx.x >> 1, half = blockIdx.x & 1;
    int row0 = tile * 64;
    for (int i = t; i < 64 * 16; i += 256) {
        int k = i >> 4, cq = i & 15;
        float4 v = ((const float4*)(w + k * 128 + half * 64))[cq];
        ((float4*)&swh[k][cq * 4])[0] = v;
    }
    for (int i = t; i < 64 * 16; i += 256) {
        int r = i >> 4, kq = i & 15;
        int row = row0 + r;
        float4 v = make_float4(0.f, 0.f, 0.f, 0.f);
        if (row < N_NODES) v = ((const float4*)a)[row * 16 + kq];
        int k = kq * 4;
        sxT[k][r] = v.x; sxT[k + 1][r] = v.y; sxT[k + 2][r] = v.z; sxT[k + 3][r] = v.w;
    }
    __syncthreads();
    float acc[4][4] = {};
    for (int k = 0; k < 64; ++k) {
        float4 av = *(const float4*)&sxT[k][ty * 4];
        float4 bb = *(const float4*)&swh[k][tx * 4];
        acc[0][0] += av.x * bb.x; acc[0][1] += av.x * bb.y; acc[0][2] += av.x * bb.z; acc[0][3] += av.x * bb.w;
        acc[1][0] += av.y * bb.x; acc[1][1] += av.y * bb.y; acc[1][2] += av.y * bb.z; acc[1][3] += av.y * bb.w;
        acc[2][0] += av.z * bb.x; acc[2][1] += av.z * bb.y; acc[2][2] += av.z * bb.z; acc[2][3] += av.z * bb.w;
        acc[3][0] += av.w * bb.x; acc[3][1] += av.w * bb.y; acc[3][2] += av.w * bb.z; acc[3][3] += av.w * bb.w;
    }
    float as0 = att_src[half * 64 + tx * 4],     as1 = att_src[half * 64 + tx * 4 + 1];
    float as2 = att_src[half * 64 + tx * 4 + 2], as3 = att_src[half * 64 + tx * 4 + 3];
    float ad0 = att_dst[half * 64 + tx * 4],     ad1 = att_dst[half * 64 + tx * 4 + 1];
    float ad2 = att_dst[half * 64 + tx * 4 + 2], ad3 = att_dst[half * 64 + tx * 4 + 3];
    #pragma unroll
    for (int i = 0; i < 4; ++i) {
        int row = row0 + ty * 4 + i;
        float ps = acc[i][0] * as0 + acc[i][1] * as1 + acc[i][2] * as2 + acc[i][3] * as3;
        float pd = acc[i][0] * ad0 + acc[i][1] * ad1 + acc[i][2] * ad2 + acc[i][3] * ad3;
        #pragma unroll
        for (int off = 1; off < 16; off <<= 1) {   // reduce over 16 lanes sharing this row
            ps += __shfl_xor(ps, off, 64);
            pd += __shfl_xor(pd, off, 64);
        }
        if (row < N_NODES) {
            if (tx == 0) { ss[row * 2 + half] = ps; sd[row * 2 + half] = pd; }
            ushort4 o;
            o.x = f2h(acc[i][0]); o.y = f2h(acc[i][1]); o.z = f2h(acc[i][2]); o.w = f2h(acc[i][3]);
            h2h[row * 32 + half * 16 + tx] = o;   // row stride = 128 halves = 32 ushort4
        }
    }
}

// ---------------- segment gather kernels ----------------

// GCN: wave = node; lanes = 8 edge-groups x 8 (8 fp16 channels via uint4).
// norm computed on the fly: dinv[d] * sum(dinv[s]*ew * h1[s])  (+ self dinv[d]^2 h1[d])
__global__ void k_gcn_csr(const int* __restrict__ rowptr, const int2* __restrict__ ep,
                          const float* __restrict__ dinv,
                          const uint4* __restrict__ h1q, const float* __restrict__ b,
                          float4* __restrict__ agg1v) {
    int t = threadIdx.x;
    int n = blockIdx.x * 4 + (t >> 6);
    if (n >= N_NODES) return;
    int lane = t & 63, q = lane >> 3, r = lane & 7;
    int r0 = rowptr[n], r1 = rowptr[n + 1];
    float dn = dinv[n];
    float acc[8] = {};
    if (q == 0) {
        float f[8]; h8f(h1q[n * 8 + r], f);
        #pragma unroll
        for (int j = 0; j < 8; ++j) acc[j] = dn * f[j];
    }
    for (int i = r0 + q; i < r1; i += 8) {
        int2 e = ep[i];
        float wl = dinv[e.x] * __int_as_float(e.y);
        float f[8]; h8f(h1q[e.x * 8 + r], f);
        #pragma unroll
        for (int j = 0; j < 8; ++j) acc[j] += wl * f[j];
    }
    #pragma unroll
    for (int off = 8; off < 64; off <<= 1) {
        #pragma unroll
        for (int j = 0; j < 8; ++j) acc[j] += __shfl_xor(acc[j], off, 64);
    }
    if (q == 0) {
        float4 b0 = ((const float4*)b)[2 * r], b1 = ((const float4*)b)[2 * r + 1];
        agg1v[n * 16 + 2 * r] = make_float4(fmaxf(acc[0] * dn + b0.x, 0.f), fmaxf(acc[1] * dn + b0.y, 0.f),
                                            fmaxf(acc[2] * dn + b0.z, 0.f), fmaxf(acc[3] * dn + b0.w, 0.f));
        agg1v[n * 16 + 2 * r + 1] = make_float4(fmaxf(acc[4] * dn + b1.x, 0.f), fmaxf(acc[5] * dn + b1.y, 0.f),
                                                fmaxf(acc[6] * dn + b1.z, 0.f), fmaxf(acc[7] * dn + b1.w, 0.f));
    }
}

// GAT: block=128 -> 1 node; wave = head; lanes = 8 edge-groups x 8 (8 fp16 ch via uint4).
// No max pass: scores are O(+-few), exp cannot overflow fp32; softmax shift-invariant.
__global__ void k_gat_csr(const int* __restrict__ rowptr, const int2* __restrict__ ep,
                          const float* __restrict__ ss, const float* __restrict__ sd,
                          const uint4* __restrict__ h2q, const float* __restrict__ b,
                          float* __restrict__ out) {
    __shared__ __align__(16) float lds[2][64];
    int n = blockIdx.x;
    int t = threadIdx.x;
    int head = t >> 6, lane = t & 63;
    int q = lane >> 3, r = lane & 7;
    int r0 = rowptr[n], r1 = rowptr[n + 1];
    float sdn = sd[n * 2 + head];
    float den = 0.f;
    float acc[8] = {};
    if (q == 0) {
        float exs = __expf(leaky(ss[n * 2 + head] + sdn));
        den = exs;
        float f[8]; h8f(h2q[n * 16 + head * 8 + r], f);
        #pragma unroll
        for (int j = 0; j < 8; ++j) acc[j] = exs * f[j];
    }
    for (int i = r0 + q; i < r1; i += 8) {
        int s = ep[i].x;
        float ex = __expf(leaky(ss[s * 2 + head] + sdn));
        den += ex;
        float f[8]; h8f(h2q[s * 16 + head * 8 + r], f);
        #pragma unroll
        for (int j = 0; j < 8; ++j) acc[j] += ex * f[j];
    }
    #pragma unroll
    for (int off = 8; off < 64; off <<= 1) {
        #pragma unroll
        for (int j = 0; j < 8; ++j) acc[j] += __shfl_xor(acc[j], off, 64);
        den += __shfl_xor(den, off, 64);
    }
    if (q == 0) {
        float inv = 1.0f / fmaxf(den, 1e-16f);
        *(float4*)&lds[head][r * 8]     = make_float4(acc[0] * inv, acc[1] * inv, acc[2] * inv, acc[3] * inv);
        *(float4*)&lds[head][r * 8 + 4] = make_float4(acc[4] * inv, acc[5] * inv, acc[6] * inv, acc[7] * inv);
    }
    __syncthreads();
    if (t < 64) {
        float v = 0.5f * (lds[0][t] + lds[1][t]) + b[t];
        out[n * 64 + t] = fmaxf(v, 0.0f);
    }
}

// ---------------- launch ----------------
extern "C" void kernel_launch(void* const* d_in, const int* in_sizes, int n_in,
                              void* d_out, int out_size, void* d_ws, size_t ws_size,
                              hipStream_t stream) {
    const float* x       = (const float*)d_in[0];
    const int*   eidx    = (const int*)d_in[1];
    const float* ew      = (const float*)d_in[2];
    const float* gcn_w   = (const float*)d_in[3];
    const float* gcn_b   = (const float*)d_in[4];
    const float* gat_w   = (const float*)d_in[5];
    const float* att_src = (const float*)d_in[6];
    const float* att_dst = (const float*)d_in[7];
    const float* gat_b   = (const float*)d_in[8];
    float* out = (float*)d_out;

    const int* src = eidx;            // edge_index[0]
    const int* dst = eidx + N_EDGES;  // edge_index[1]

    // workspace layout (16B-aligned blocks first)
    char* p = (char*)d_ws;
    float* agg1   = (float*)p;  p += sizeof(float) * (size_t)N_NODES * 64;    // fp32 gemm2 input
    ushort* h1h   = (ushort*)p; p += sizeof(ushort) * (size_t)N_NODES * 64;   // fp16
    ushort* h2h   = (ushort*)p; p += sizeof(ushort) * (size_t)N_NODES * 128;  // fp16
    int2*  ep     = (int2*)p;   p += sizeof(int2) * (size_t)N_EDGES;          // {src, ew}
    int*   count  = (int*)p;    p += sizeof(int) * N_NODES;
    float* dinv   = (float*)p;  p += sizeof(float) * N_NODES;
    int*   incl   = (int*)p;    p += sizeof(int) * N_NODES;
    int*   rowptr = (int*)p;    p += sizeof(int) * (N_NODES + 1);
    int*   cursor = (int*)p;    p += sizeof(int) * N_NODES;
    float* ss     = (float*)p;  p += sizeof(float) * N_NODES * 2;
    float* sd     = (float*)p;  p += sizeof(float) * N_NODES * 2;
    int*   bsum   = (int*)p;    p += sizeof(int) * NB_SCAN;
    int*   boff   = (int*)p;    p += sizeof(int) * NB_SCAN;

    const int T = 256;
    const int NBe8 = 8 * ((N_EDGES + T - 1) / T);   // sharded edge grids

    // CSR build
    hipMemsetAsync(count, 0, sizeof(int) * N_NODES, stream);
    k_count<<<NBe8, T, 0, stream>>>(dst, count);
    k_scan_a<<<NB_SCAN, T, 0, stream>>>(count, incl, bsum);
    k_scan_b<<<1, 512, 0, stream>>>(bsum, boff);
    k_scan_c<<<NB_SCAN, T, 0, stream>>>(count, incl, boff, rowptr, cursor);
    k_scatter<<<NBe8, T, 0, stream>>>(src, dst, ew, cursor, ep);
    k_deg_dinv<<<NB_SCAN, T, 0, stream>>>(rowptr, ep, dinv);

    // layer 1: GCN
    k_gemm1<<<(N_NODES + 63) / 64, T, 0, stream>>>(x, gcn_w, (ushort4*)h1h);
    k_gcn_csr<<<(N_NODES + 3) / 4, T, 0, stream>>>(rowptr, ep, dinv, (const uint4*)h1h, gcn_b, (float4*)agg1);

    // layer 2: GAT (scores fused into gemm2 epilogue)
    k_gemm2<<<((N_NODES + 63) / 64) * 2, T, 0, stream>>>(agg1, gat_w, att_src, att_dst, (ushort4*)h2h, ss, sd);
    k_gat_csr<<<N_NODES, 128, 0, stream>>>(rowptr, ep, ss, sd, (const uint4*)h2h, gat_b, out);
}

// Round 7
// 457.816 us; speedup vs baseline: 3.9447x; 1.0400x over previous
//
#include <hip/hip_runtime.h>
#include <hip/hip_fp16.h>
#include <math.h>

#define N_NODES 100000
#define N_EDGES 1600000
#define IN_CH 128
#define HID 64
#define HEADS 2
#define NEG_SLOPE 0.2f

#define NB_SCAN ((N_NODES + 255) / 256)   // 391 scan blocks
#define SHARD_SZ 12500                    // 100000 / 8 XCD shards

static __device__ inline ushort f2h(float f) { return __half_as_ushort(__float2half(f)); }
static __device__ inline float h2f(ushort u) { return __half2float(__ushort_as_half(u)); }
static __device__ inline void h8f(uint4 u, float f[8]) {
    f[0] = h2f((ushort)(u.x & 0xffff)); f[1] = h2f((ushort)(u.x >> 16));
    f[2] = h2f((ushort)(u.y & 0xffff)); f[3] = h2f((ushort)(u.y >> 16));
    f[4] = h2f((ushort)(u.z & 0xffff)); f[5] = h2f((ushort)(u.z >> 16));
    f[6] = h2f((ushort)(u.w & 0xffff)); f[7] = h2f((ushort)(u.w >> 16));
}
static __device__ inline uint pack2(float a, float b) {
    return (uint)f2h(a) | ((uint)f2h(b) << 16);
}

__device__ inline float leaky(float a) { return (a >= 0.0f) ? a : NEG_SLOPE * a; }

// ---------------- CSR build ----------------

// plain histogram (counts are 400KB, read-mostly afterwards — sharding unnecessary)
__global__ void k_count(const int* __restrict__ dst, int* count) {
    int e = blockIdx.x * 256 + threadIdx.x;
    if (e < N_EDGES) atomicAdd(&count[dst[e]], 1);
}

__global__ void k_scan_a(const int* __restrict__ count, int* __restrict__ incl,
                         int* __restrict__ bsum) {
    __shared__ int sh[256];
    int tid = threadIdx.x;
    int g = blockIdx.x * 256 + tid;
    int v = (g < N_NODES) ? count[g] : 0;
    sh[tid] = v;
    __syncthreads();
    for (int off = 1; off < 256; off <<= 1) {
        int t = (tid >= off) ? sh[tid - off] : 0;
        __syncthreads();
        sh[tid] += t;
        __syncthreads();
    }
    if (g < N_NODES) incl[g] = sh[tid];
    if (tid == 255) bsum[blockIdx.x] = sh[255];
}

__global__ void k_scan_b(const int* __restrict__ bsum, int* __restrict__ boff) {
    __shared__ int sh[512];
    int tid = threadIdx.x;
    int v = (tid < NB_SCAN) ? bsum[tid] : 0;
    sh[tid] = v;
    __syncthreads();
    for (int off = 1; off < 512; off <<= 1) {
        int t = (tid >= off) ? sh[tid - off] : 0;
        __syncthreads();
        sh[tid] += t;
        __syncthreads();
    }
    if (tid < NB_SCAN) boff[tid] = sh[tid] - v;   // exclusive
}

__global__ void k_scan_c(const int* __restrict__ count, const int* __restrict__ incl,
                         const int* __restrict__ boff, int* rowptr, int* cursor) {
    int g = blockIdx.x * 256 + threadIdx.x;
    if (g >= N_NODES) return;
    int excl = incl[g] - count[g] + boff[blockIdx.x];
    rowptr[g] = excl;
    cursor[g] = excl;
    if (g == N_NODES - 1) rowptr[N_NODES] = incl[g] + boff[blockIdx.x];
}

// sharded scatter: one 8B store {src, raw ew} per edge; writes + cursor atomics XCD-local
__global__ void k_scatter(const int* __restrict__ src, const int* __restrict__ dst,
                          const float* __restrict__ ew,
                          int* cursor, int2* __restrict__ ep) {
    int shard = blockIdx.x & 7;
    int e = (blockIdx.x >> 3) * 256 + threadIdx.x;
    if (e >= N_EDGES) return;
    int d = dst[e];
    if (d / SHARD_SZ != shard) return;
    int pos = atomicAdd(&cursor[d], 1);
    ep[pos] = make_int2(src[e], __float_as_int(ew[e]));
}

// deg/dinv from CSR: coalesced sequential reads, no atomics. deg = 1 (self-loop) + sum ew.
__global__ void k_deg_dinv(const int* __restrict__ rowptr, const int2* __restrict__ ep,
                           float* __restrict__ dinv) {
    int n = blockIdx.x * 256 + threadIdx.x;
    if (n >= N_NODES) return;
    int r0 = rowptr[n], r1 = rowptr[n + 1];
    float deg = 1.0f;
    for (int i = r0; i < r1; ++i) deg += __int_as_float(ep[i].y);
    dinv[n] = rsqrtf(deg);
}

// ---------------- dense: register-tiled GEMMs, padded LDS (no 32-way conflicts) ------

// h1 = x @ gcn_w   [N,128]@[128,64] -> fp16.  K staged in two 64-chunks.
__global__ __launch_bounds__(256) void k_gemm1(const float* __restrict__ x,
                                               const float* __restrict__ w,
                                               ushort4* __restrict__ h1h) {
    __shared__ float sxT[64][65];    // [k][r], +1 pad: transpose store <=2-way conflict
    __shared__ float sw[128][64];    // [k][c]
    int t = threadIdx.x;
    int tx = t & 15, ty = t >> 4;
    int row0 = blockIdx.x * 64;
    for (int i = t; i < 128 * 16; i += 256)
        ((float4*)sw)[i] = ((const float4*)w)[i];
    float acc[4][4] = {};
    for (int c = 0; c < 2; ++c) {
        __syncthreads();   // chunk reuse guard (also orders after w staging for c=0)
        for (int i = t; i < 64 * 16; i += 256) {
            int r = i >> 4, kq = i & 15;
            int row = row0 + r;
            float4 v = make_float4(0.f, 0.f, 0.f, 0.f);
            if (row < N_NODES) v = ((const float4*)x)[row * 32 + c * 16 + kq];
            int k = kq * 4;
            sxT[k][r] = v.x; sxT[k + 1][r] = v.y; sxT[k + 2][r] = v.z; sxT[k + 3][r] = v.w;
        }
        __syncthreads();
        #pragma unroll 8
        for (int k = 0; k < 64; ++k) {
            float a0 = sxT[k][ty * 4], a1 = sxT[k][ty * 4 + 1];
            float a2 = sxT[k][ty * 4 + 2], a3 = sxT[k][ty * 4 + 3];
            float4 bb = *(const float4*)&sw[c * 64 + k][tx * 4];
            acc[0][0] += a0 * bb.x; acc[0][1] += a0 * bb.y; acc[0][2] += a0 * bb.z; acc[0][3] += a0 * bb.w;
            acc[1][0] += a1 * bb.x; acc[1][1] += a1 * bb.y; acc[1][2] += a1 * bb.z; acc[1][3] += a1 * bb.w;
            acc[2][0] += a2 * bb.x; acc[2][1] += a2 * bb.y; acc[2][2] += a2 * bb.z; acc[2][3] += a2 * bb.w;
            acc[3][0] += a3 * bb.x; acc[3][1] += a3 * bb.y; acc[3][2] += a3 * bb.z; acc[3][3] += a3 * bb.w;
        }
    }
    #pragma unroll
    for (int i = 0; i < 4; ++i) {
        int row = row0 + ty * 4 + i;
        if (row < N_NODES) {
            ushort4 o;
            o.x = f2h(acc[i][0]); o.y = f2h(acc[i][1]); o.z = f2h(acc[i][2]); o.w = f2h(acc[i][3]);
            h1h[row * 16 + tx] = o;
        }
    }
}

// h2 = agg1(fp16) @ gat_w [N,64]@[64,128] -> fp16; grid = tiles x 2 column halves.
// half == head: fused attention scores ss/sd from fp32 acc in epilogue.
__global__ __launch_bounds__(256) void k_gemm2(const uint4* __restrict__ a16,
                                               const float* __restrict__ w,
                                               const float* __restrict__ att_src,
                                               const float* __restrict__ att_dst,
                                               ushort4* __restrict__ h2h,
                                               float* __restrict__ ss, float* __restrict__ sd) {
    __shared__ float sxT[64][65];    // [k][r] padded
    __shared__ float swh[64][64];    // [k][c] (column half)
    int t = threadIdx.x;
    int tx = t & 15, ty = t >> 4;
    int tile = blockIdx.x >> 1, half = blockIdx.x & 1;
    int row0 = tile * 64;
    for (int i = t; i < 64 * 16; i += 256) {
        int k = i >> 4, cq = i & 15;
        float4 v = ((const float4*)(w + k * 128 + half * 64))[cq];
        ((float4*)&swh[k][cq * 4])[0] = v;
    }
    for (int i = t; i < 64 * 8; i += 256) {   // a tile: 64 rows x 8 uint4 (8 halves each)
        int r = i >> 3, j = i & 7;
        int row = row0 + r;
        float f[8] = {};
        if (row < N_NODES) { uint4 u = a16[row * 8 + j]; h8f(u, f); }
        int k = j * 8;
        #pragma unroll
        for (int m = 0; m < 8; ++m) sxT[k + m][r] = f[m];
    }
    __syncthreads();
    float acc[4][4] = {};
    #pragma unroll 8
    for (int k = 0; k < 64; ++k) {
        float a0 = sxT[k][ty * 4], a1 = sxT[k][ty * 4 + 1];
        float a2 = sxT[k][ty * 4 + 2], a3 = sxT[k][ty * 4 + 3];
        float4 bb = *(const float4*)&swh[k][tx * 4];
        acc[0][0] += a0 * bb.x; acc[0][1] += a0 * bb.y; acc[0][2] += a0 * bb.z; acc[0][3] += a0 * bb.w;
        acc[1][0] += a1 * bb.x; acc[1][1] += a1 * bb.y; acc[1][2] += a1 * bb.z; acc[1][3] += a1 * bb.w;
        acc[2][0] += a2 * bb.x; acc[2][1] += a2 * bb.y; acc[2][2] += a2 * bb.z; acc[2][3] += a2 * bb.w;
        acc[3][0] += a3 * bb.x; acc[3][1] += a3 * bb.y; acc[3][2] += a3 * bb.z; acc[3][3] += a3 * bb.w;
    }
    float as0 = att_src[half * 64 + tx * 4],     as1 = att_src[half * 64 + tx * 4 + 1];
    float as2 = att_src[half * 64 + tx * 4 + 2], as3 = att_src[half * 64 + tx * 4 + 3];
    float ad0 = att_dst[half * 64 + tx * 4],     ad1 = att_dst[half * 64 + tx * 4 + 1];
    float ad2 = att_dst[half * 64 + tx * 4 + 2], ad3 = att_dst[half * 64 + tx * 4 + 3];
    #pragma unroll
    for (int i = 0; i < 4; ++i) {
        int row = row0 + ty * 4 + i;
        float ps = acc[i][0] * as0 + acc[i][1] * as1 + acc[i][2] * as2 + acc[i][3] * as3;
        float pd = acc[i][0] * ad0 + acc[i][1] * ad1 + acc[i][2] * ad2 + acc[i][3] * ad3;
        #pragma unroll
        for (int off = 1; off < 16; off <<= 1) {
            ps += __shfl_xor(ps, off, 64);
            pd += __shfl_xor(pd, off, 64);
        }
        if (row < N_NODES) {
            if (tx == 0) { ss[row * 2 + half] = ps; sd[row * 2 + half] = pd; }
            ushort4 o;
            o.x = f2h(acc[i][0]); o.y = f2h(acc[i][1]); o.z = f2h(acc[i][2]); o.w = f2h(acc[i][3]);
            h2h[row * 32 + half * 16 + tx] = o;
        }
    }
}

// ---------------- segment gather kernels ----------------

// GCN: wave = node; lanes = 8 edge-groups x 8 (8 fp16 channels via uint4). fp16 output.
__global__ void k_gcn_csr(const int* __restrict__ rowptr, const int2* __restrict__ ep,
                          const float* __restrict__ dinv,
                          const uint4* __restrict__ h1q, const float* __restrict__ b,
                          uint4* __restrict__ agg1h) {
    int t = threadIdx.x;
    int n = blockIdx.x * 4 + (t >> 6);
    if (n >= N_NODES) return;
    int lane = t & 63, q = lane >> 3, r = lane & 7;
    int r0 = rowptr[n], r1 = rowptr[n + 1];
    float dn = dinv[n];
    float acc[8] = {};
    if (q == 0) {
        float f[8]; h8f(h1q[n * 8 + r], f);
        #pragma unroll
        for (int j = 0; j < 8; ++j) acc[j] = dn * f[j];
    }
    for (int i = r0 + q; i < r1; i += 8) {
        int2 e = ep[i];
        float wl = dinv[e.x] * __int_as_float(e.y);
        float f[8]; h8f(h1q[e.x * 8 + r], f);
        #pragma unroll
        for (int j = 0; j < 8; ++j) acc[j] += wl * f[j];
    }
    #pragma unroll
    for (int off = 8; off < 64; off <<= 1) {
        #pragma unroll
        for (int j = 0; j < 8; ++j) acc[j] += __shfl_xor(acc[j], off, 64);
    }
    if (q == 0) {
        float4 b0 = ((const float4*)b)[2 * r], b1 = ((const float4*)b)[2 * r + 1];
        float v0 = fmaxf(acc[0] * dn + b0.x, 0.f), v1 = fmaxf(acc[1] * dn + b0.y, 0.f);
        float v2 = fmaxf(acc[2] * dn + b0.z, 0.f), v3 = fmaxf(acc[3] * dn + b0.w, 0.f);
        float v4 = fmaxf(acc[4] * dn + b1.x, 0.f), v5 = fmaxf(acc[5] * dn + b1.y, 0.f);
        float v6 = fmaxf(acc[6] * dn + b1.z, 0.f), v7 = fmaxf(acc[7] * dn + b1.w, 0.f);
        uint4 o;
        o.x = pack2(v0, v1); o.y = pack2(v2, v3); o.z = pack2(v4, v5); o.w = pack2(v6, v7);
        agg1h[n * 8 + r] = o;
    }
}

// GAT: block=128 -> 1 node; wave = head; lanes = 8 edge-groups x 8 (8 fp16 ch via uint4).
// No max pass: scores are O(+-few), exp cannot overflow fp32; softmax shift-invariant.
__global__ void k_gat_csr(const int* __restrict__ rowptr, const int2* __restrict__ ep,
                          const float* __restrict__ ss, const float* __restrict__ sd,
                          const uint4* __restrict__ h2q, const float* __restrict__ b,
                          float* __restrict__ out) {
    __shared__ __align__(16) float lds[2][64];
    int n = blockIdx.x;
    int t = threadIdx.x;
    int head = t >> 6, lane = t & 63;
    int q = lane >> 3, r = lane & 7;
    int r0 = rowptr[n], r1 = rowptr[n + 1];
    float sdn = sd[n * 2 + head];
    float den = 0.f;
    float acc[8] = {};
    if (q == 0) {
        float exs = __expf(leaky(ss[n * 2 + head] + sdn));
        den = exs;
        float f[8]; h8f(h2q[n * 16 + head * 8 + r], f);
        #pragma unroll
        for (int j = 0; j < 8; ++j) acc[j] = exs * f[j];
    }
    for (int i = r0 + q; i < r1; i += 8) {
        int s = ep[i].x;
        float ex = __expf(leaky(ss[s * 2 + head] + sdn));
        den += ex;
        float f[8]; h8f(h2q[s * 16 + head * 8 + r], f);
        #pragma unroll
        for (int j = 0; j < 8; ++j) acc[j] += ex * f[j];
    }
    #pragma unroll
    for (int off = 8; off < 64; off <<= 1) {
        #pragma unroll
        for (int j = 0; j < 8; ++j) acc[j] += __shfl_xor(acc[j], off, 64);
        den += __shfl_xor(den, off, 64);
    }
    if (q == 0) {
        float inv = 1.0f / fmaxf(den, 1e-16f);
        *(float4*)&lds[head][r * 8]     = make_float4(acc[0] * inv, acc[1] * inv, acc[2] * inv, acc[3] * inv);
        *(float4*)&lds[head][r * 8 + 4] = make_float4(acc[4] * inv, acc[5] * inv, acc[6] * inv, acc[7] * inv);
    }
    __syncthreads();
    if (t < 64) {
        float v = 0.5f * (lds[0][t] + lds[1][t]) + b[t];
        out[n * 64 + t] = fmaxf(v, 0.0f);
    }
}

// ---------------- launch ----------------
extern "C" void kernel_launch(void* const* d_in, const int* in_sizes, int n_in,
                              void* d_out, int out_size, void* d_ws, size_t ws_size,
                              hipStream_t stream) {
    const float* x       = (const float*)d_in[0];
    const int*   eidx    = (const int*)d_in[1];
    const float* ew      = (const float*)d_in[2];
    const float* gcn_w   = (const float*)d_in[3];
    const float* gcn_b   = (const float*)d_in[4];
    const float* gat_w   = (const float*)d_in[5];
    const float* att_src = (const float*)d_in[6];
    const float* att_dst = (const float*)d_in[7];
    const float* gat_b   = (const float*)d_in[8];
    float* out = (float*)d_out;

    const int* src = eidx;            // edge_index[0]
    const int* dst = eidx + N_EDGES;  // edge_index[1]

    // workspace layout (16B-aligned blocks first)
    char* p = (char*)d_ws;
    ushort* agg1h = (ushort*)p; p += sizeof(ushort) * (size_t)N_NODES * 64;   // fp16
    ushort* h1h   = (ushort*)p; p += sizeof(ushort) * (size_t)N_NODES * 64;   // fp16
    ushort* h2h   = (ushort*)p; p += sizeof(ushort) * (size_t)N_NODES * 128;  // fp16
    int2*  ep     = (int2*)p;   p += sizeof(int2) * (size_t)N_EDGES;          // {src, ew}
    int*   count  = (int*)p;    p += sizeof(int) * N_NODES;
    float* dinv   = (float*)p;  p += sizeof(float) * N_NODES;
    int*   incl   = (int*)p;    p += sizeof(int) * N_NODES;
    int*   rowptr = (int*)p;    p += sizeof(int) * (N_NODES + 1);
    int*   cursor = (int*)p;    p += sizeof(int) * N_NODES;
    float* ss     = (float*)p;  p += sizeof(float) * N_NODES * 2;
    float* sd     = (float*)p;  p += sizeof(float) * N_NODES * 2;
    int*   bsum   = (int*)p;    p += sizeof(int) * NB_SCAN;
    int*   boff   = (int*)p;    p += sizeof(int) * NB_SCAN;

    const int T = 256;
    const int NBe  = (N_EDGES + T - 1) / T;
    const int NBe8 = 8 * NBe;   // sharded scatter grid

    // CSR build
    hipMemsetAsync(count, 0, sizeof(int) * N_NODES, stream);
    k_count<<<NBe, T, 0, stream>>>(dst, count);
    k_scan_a<<<NB_SCAN, T, 0, stream>>>(count, incl, bsum);
    k_scan_b<<<1, 512, 0, stream>>>(bsum, boff);
    k_scan_c<<<NB_SCAN, T, 0, stream>>>(count, incl, boff, rowptr, cursor);
    k_scatter<<<NBe8, T, 0, stream>>>(src, dst, ew, cursor, ep);
    k_deg_dinv<<<NB_SCAN, T, 0, stream>>>(rowptr, ep, dinv);

    // layer 1: GCN
    k_gemm1<<<(N_NODES + 63) / 64, T, 0, stream>>>(x, gcn_w, (ushort4*)h1h);
    k_gcn_csr<<<(N_NODES + 3) / 4, T, 0, stream>>>(rowptr, ep, dinv, (const uint4*)h1h, gcn_b, (uint4*)agg1h);

    // layer 2: GAT (scores fused into gemm2 epilogue)
    k_gemm2<<<((N_NODES + 63) / 64) * 2, T, 0, stream>>>((const uint4*)agg1h, gat_w, att_src, att_dst, (ushort4*)h2h, ss, sd);
    k_gat_csr<<<N_NODES, 128, 0, stream>>>(rowptr, ep, ss, sd, (const uint4*)h2h, gat_b, out);
}